// Round 1
// baseline (417.669 us; speedup 1.0000x reference)
//
#include <hip/hip_runtime.h>

// 8-level DWT (fixed 10-tap filters) + 8-level per-channel IDWT (32-tap learned filters).
// Correctness-first implementation: one thread per output element, 16 launches.

static __constant__ float c_dec_lo[10] = {
    0.003335725285001549f, -0.012580751999015526f, -0.006241490213011705f,
    0.07757149384006515f, -0.03224486958502952f, -0.24229488706619015f,
    0.13842814590110342f, 0.7243085284385744f, 0.6038292697974729f,
    0.160102397974125f};
static __constant__ float c_dec_hi[10] = {
    -0.160102397974125f, 0.6038292697974729f, -0.7243085284385744f,
    0.13842814590110342f, 0.24229488706619015f, -0.03224486958502952f,
    -0.07757149384006515f, -0.006241490213011705f, 0.012580751999015526f,
    0.003335725285001549f};

// Forward: lo'[b][d] = sum_k in[b][2d-5+k]*w_lo[k]; hi analogous.
// in: row stride L; outputs: row stride D.
__global__ __launch_bounds__(256) void fwd_level(
    const float* __restrict__ in, float* __restrict__ lo_out,
    float* __restrict__ hi_out, int L, int D) {
  int d = blockIdx.x * blockDim.x + threadIdx.x;
  int b = blockIdx.y;
  if (d >= D) return;
  const float* row = in + (size_t)b * (size_t)L;
  int base = 2 * d - 5;
  float slo = 0.f, shi = 0.f;
#pragma unroll
  for (int k = 0; k < 10; ++k) {
    int j = base + k;
    float v = (j >= 0 && j < L) ? row[j] : 0.f;
    slo += v * c_dec_lo[k];
    shi += v * c_dec_hi[k];
  }
  lo_out[(size_t)b * D + d] = slo;
  hi_out[(size_t)b * D + d] = shi;
}

// Inverse level i:
// y[c][t] = sum over k (k parity == (t-15) parity), j=(t-15+k)/2 in [0,L):
//           prev[c][j]*w_lo[c][k] + hi[c][j]*w_hi[c][k]
// filt layout: [c][8][2][32]
__global__ __launch_bounds__(256) void inv_level(
    const float* __restrict__ prev, const float* __restrict__ hicoef,
    const float* __restrict__ filt, int level, int L, int Tout,
    float* __restrict__ out) {
  int c = blockIdx.y;
  __shared__ float wlo[32];
  __shared__ float whi[32];
  int tid = threadIdx.x;
  if (tid < 32) {
    wlo[tid] = filt[((size_t)c * 8 + level) * 64 + tid];
  } else if (tid < 64) {
    whi[tid - 32] = filt[((size_t)c * 8 + level) * 64 + tid];
  }
  __syncthreads();
  int t = blockIdx.x * blockDim.x + tid;
  if (t >= Tout) return;
  const float* prow = prev + (size_t)c * L;
  const float* hrow = hicoef + (size_t)c * L;
  int a = t - 15;
  int k0 = a & 1;  // taps with (a+k) even
  float s = 0.f;
#pragma unroll
  for (int m = 0; m < 16; ++m) {
    int k = k0 + 2 * m;
    int j = (a + k) >> 1;  // exact: a+k is even
    if (j >= 0 && j < L) {
      s += prow[j] * wlo[k] + hrow[j] * whi[k];
    }
  }
  out[(size_t)c * Tout + t] = s;
}

extern "C" void kernel_launch(void* const* d_in, const int* in_sizes, int n_in,
                              void* d_out, int out_size, void* d_ws,
                              size_t ws_size, hipStream_t stream) {
  const float* x = (const float*)d_in[0];
  const float* filt = (const float*)d_in[1];
  float* out = (float*)d_out;
  float* ws = (float*)d_ws;

  const int B = 128;
  const int T = 131072;
  static const int Dl[8] = {65537, 32769, 16385, 8193, 4097, 2049, 1025, 513};

  size_t pingSz = (size_t)B * 65537;
  float* pp[2] = {ws, ws + pingSz};
  float* hiBase = ws + 2 * pingSz;
  float* hi[8];
  size_t off = 0;
  for (int l = 0; l < 8; ++l) {
    hi[l] = hiBase + off;
    off += (size_t)B * Dl[l];
  }

  // ---- forward DWT ----
  const float* cur = x;
  int L = T;
  for (int l = 0; l < 8; ++l) {
    int D = Dl[l];
    float* lo_out = pp[l & 1];
    dim3 grid((D + 255) / 256, B);
    hipLaunchKernelGGL(fwd_level, grid, dim3(256), 0, stream, cur, lo_out,
                       hi[l], L, D);
    cur = lo_out;
    L = D;
  }
  // final lo lives in pp[1] (length 513 per row)

  // ---- inverse DWT ----
  const float* prev = cur;
  for (int i = 7; i >= 0; --i) {
    int Lc = Dl[i];
    int Tout = (i == 0) ? T : 2 * Lc - 1;
    float* dst = (i == 0) ? out : pp[(i + 1) & 1];
    dim3 grid((Tout + 255) / 256, B);
    hipLaunchKernelGGL(inv_level, grid, dim3(256), 0, stream, prev, hi[i], filt,
                       i, Lc, Tout, dst);
    prev = dst;
  }
}

// Round 2
// 211.388 us; speedup vs baseline: 1.9758x; 1.9758x over previous
//
#include <hip/hip_runtime.h>

// 8-level DWT (fixed 10-tap) + 8-level per-channel IDWT (32-tap learned),
// restructured as dense polyphase FIRs with vectorized register windows.

static __constant__ float c_dec_lo[10] = {
    0.003335725285001549f, -0.012580751999015526f, -0.006241490213011705f,
    0.07757149384006515f, -0.03224486958502952f, -0.24229488706619015f,
    0.13842814590110342f, 0.7243085284385744f, 0.6038292697974729f,
    0.160102397974125f};
static __constant__ float c_dec_hi[10] = {
    -0.160102397974125f, 0.6038292697974729f, -0.7243085284385744f,
    0.13842814590110342f, 0.24229488706619015f, -0.03224486958502952f,
    -0.07757149384006515f, -0.006241490213011705f, 0.012580751999015526f,
    0.003335725285001549f};

// Zero-padded aligned vector load: row is 16B-aligned, j % 4 == 0.
__device__ inline float4 ldz4(const float* __restrict__ row, int j, int L) {
  if (j >= 0 && j + 3 < L) {
    return *reinterpret_cast<const float4*>(row + j);
  }
  float4 r;
  r.x = (j + 0 >= 0 && j + 0 < L) ? row[j + 0] : 0.f;
  r.y = (j + 1 >= 0 && j + 1 < L) ? row[j + 1] : 0.f;
  r.z = (j + 2 >= 0 && j + 2 < L) ? row[j + 2] : 0.f;
  r.w = (j + 3 >= 0 && j + 3 < L) ? row[j + 3] : 0.f;
  return r;
}

// Forward level: lo[d] = sum_k in[2d-5+k]*w_lo[k], hi analogous.
// Each thread computes DPT=4 consecutive d. Window j in [2d0-5, 2d0+10],
// loaded as 20 floats from aligned base 2d0-8.
__global__ __launch_bounds__(256) void fwd_level(
    const float* __restrict__ in, float* __restrict__ lo_out,
    float* __restrict__ hi_out, int L, int strideIn, int D, int strideOut) {
  const int b = blockIdx.y;
  const int d0 = (blockIdx.x * 256 + threadIdx.x) * 4;
  if (d0 >= D) return;
  const float* row = in + (size_t)b * (size_t)strideIn;

  float v[20];
  const int jb = 2 * d0 - 8;
#pragma unroll
  for (int q = 0; q < 5; ++q) {
    float4 t = ldz4(row, jb + 4 * q, L);
    v[4 * q + 0] = t.x;
    v[4 * q + 1] = t.y;
    v[4 * q + 2] = t.z;
    v[4 * q + 3] = t.w;
  }

  float slo[4], shi[4];
#pragma unroll
  for (int i = 0; i < 4; ++i) {
    float a = 0.f, h = 0.f;
#pragma unroll
    for (int k = 0; k < 10; ++k) {
      float x = v[2 * i + 3 + k];  // j = 2(d0+i)-5+k  ->  idx = 2i+3+k
      a += x * c_dec_lo[k];
      h += x * c_dec_hi[k];
    }
    slo[i] = a;
    shi[i] = h;
  }

  float* lo_row = lo_out + (size_t)b * strideOut;
  float* hi_row = hi_out + (size_t)b * strideOut;
  if (d0 + 3 < D) {
    *reinterpret_cast<float4*>(lo_row + d0) =
        make_float4(slo[0], slo[1], slo[2], slo[3]);
    *reinterpret_cast<float4*>(hi_row + d0) =
        make_float4(shi[0], shi[1], shi[2], shi[3]);
  } else {
#pragma unroll
    for (int i = 0; i < 4; ++i) {
      if (d0 + i < D) {
        lo_row[d0 + i] = slo[i];
        hi_row[d0 + i] = shi[i];
      }
    }
  }
}

// Inverse level (polyphase):
//   y[2u+15] = sum_m prev[u+m]  *wlo[2m]   + hi[u+m]  *whi[2m]
//   y[2u+16] = sum_m prev[u+m+1]*wlo[2m+1] + hi[u+m+1]*whi[2m+1]
// Each thread handles UPT=4 consecutive u (8 consecutive outputs).
// filt layout: [c][8][2][32]; u0 starts at -8 so all t>=0 are covered.
__global__ __launch_bounds__(256) void inv_level(
    const float* __restrict__ prev, const float* __restrict__ hicoef,
    const float* __restrict__ filt, int level, int L, int strideIn, int Tout,
    int strideOut, float* __restrict__ out) {
  const int c = blockIdx.y;
  __shared__ float4 wpack[16];  // {wlo[2m], wlo[2m+1], whi[2m], whi[2m+1]}
  const int tid = threadIdx.x;
  if (tid < 16) {
    const float* f = filt + ((size_t)c * 8 + level) * 64;
    wpack[tid] =
        make_float4(f[2 * tid], f[2 * tid + 1], f[32 + 2 * tid], f[32 + 2 * tid + 1]);
  }
  __syncthreads();

  const int u0 = -8 + (blockIdx.x * 256 + tid) * 4;
  const float* prow = prev + (size_t)c * strideIn;
  const float* hrow = hicoef + (size_t)c * strideIn;

  float p[20], h[20];
#pragma unroll
  for (int q = 0; q < 5; ++q) {
    const int j = u0 + 4 * q;
    float4 a = ldz4(prow, j, L);
    p[4 * q + 0] = a.x;
    p[4 * q + 1] = a.y;
    p[4 * q + 2] = a.z;
    p[4 * q + 3] = a.w;
    float4 b = ldz4(hrow, j, L);
    h[4 * q + 0] = b.x;
    h[4 * q + 1] = b.y;
    h[4 * q + 2] = b.z;
    h[4 * q + 3] = b.w;
  }

  float acc[8] = {0.f, 0.f, 0.f, 0.f, 0.f, 0.f, 0.f, 0.f};
#pragma unroll
  for (int m = 0; m < 16; ++m) {
    const float4 w = wpack[m];
#pragma unroll
    for (int i = 0; i < 4; ++i) {
      acc[2 * i + 0] += p[i + m] * w.x + h[i + m] * w.z;
      acc[2 * i + 1] += p[i + m + 1] * w.y + h[i + m + 1] * w.w;
    }
  }

  float* orow = out + (size_t)c * strideOut;
  const int tbase = 2 * u0 + 15;
#pragma unroll
  for (int i = 0; i < 8; ++i) {
    const int t = tbase + i;
    if (t >= 0 && t < Tout) orow[t] = acc[i];
  }
}

extern "C" void kernel_launch(void* const* d_in, const int* in_sizes, int n_in,
                              void* d_out, int out_size, void* d_ws,
                              size_t ws_size, hipStream_t stream) {
  const float* x = (const float*)d_in[0];
  const float* filt = (const float*)d_in[1];
  float* out = (float*)d_out;
  float* ws = (float*)d_ws;

  const int B = 128;
  const int T = 131072;
  static const int Dl[8] = {65537, 32769, 16385, 8193, 4097, 2049, 1025, 513};
  static const int PD[8] = {65540, 32772, 16388, 8196, 4100, 2052, 1028, 516};

  const size_t pingSz = (size_t)B * 65540;
  float* pp[2] = {ws, ws + pingSz};
  float* hiBase = ws + 2 * pingSz;
  float* hi[8];
  size_t off = 0;
  for (int l = 0; l < 8; ++l) {
    hi[l] = hiBase + off;
    off += (size_t)B * PD[l];
  }

  // ---- forward DWT ----
  const float* cur = x;
  int L = T, sIn = T;
  for (int l = 0; l < 8; ++l) {
    const int D = Dl[l];
    float* lo_out = pp[l & 1];
    dim3 grid((D + 1023) / 1024, B);
    hipLaunchKernelGGL(fwd_level, grid, dim3(256), 0, stream, cur, lo_out,
                       hi[l], L, sIn, D, PD[l]);
    cur = lo_out;
    L = D;
    sIn = PD[l];
  }

  // ---- inverse DWT ----
  const float* prev = cur;  // pp[1], stride PD[7]
  int sPrev = PD[7];
  for (int i = 7; i >= 0; --i) {
    const int Lc = Dl[i];
    const int Tout = (i == 0) ? T : 2 * Lc - 1;
    const int sOut = (i == 0) ? T : PD[i - 1];
    float* dst = (i == 0) ? out : pp[(i + 1) & 1];
    const int nU = Lc + 16;  // u in [-8, Lc+7] covers all outputs
    dim3 grid((nU + 1023) / 1024, B);
    hipLaunchKernelGGL(inv_level, grid, dim3(256), 0, stream, prev, hi[i],
                       filt, i, Lc, sPrev, Tout, sOut, dst);
    prev = dst;
    sPrev = sOut;
  }
}

// Round 3
// 209.249 us; speedup vs baseline: 1.9960x; 1.0102x over previous
//
#include <hip/hip_runtime.h>

// 8-level DWT (fixed 10-tap) + 8-level per-channel IDWT (32-tap learned).
// Big levels: vectorized interior fast path, aligned float4 loads+stores.
// Small levels (fwd 4-7, inv 7-4): fused per-row kernels in LDS.

static __constant__ float c_dec_lo[10] = {
    0.003335725285001549f, -0.012580751999015526f, -0.006241490213011705f,
    0.07757149384006515f, -0.03224486958502952f, -0.24229488706619015f,
    0.13842814590110342f, 0.7243085284385744f, 0.6038292697974729f,
    0.160102397974125f};
static __constant__ float c_dec_hi[10] = {
    -0.160102397974125f, 0.6038292697974729f, -0.7243085284385744f,
    0.13842814590110342f, 0.24229488706619015f, -0.03224486958502952f,
    -0.07757149384006515f, -0.006241490213011705f, 0.012580751999015526f,
    0.003335725285001549f};

__device__ inline float4 ldz4(const float* __restrict__ row, int j, int L) {
  if (j >= 0 && j + 3 < L) return *reinterpret_cast<const float4*>(row + j);
  float4 r;
  r.x = (j + 0 >= 0 && j + 0 < L) ? row[j + 0] : 0.f;
  r.y = (j + 1 >= 0 && j + 1 < L) ? row[j + 1] : 0.f;
  r.z = (j + 2 >= 0 && j + 2 < L) ? row[j + 2] : 0.f;
  r.w = (j + 3 >= 0 && j + 3 < L) ? row[j + 3] : 0.f;
  return r;
}

// ---------------- big forward level: 8 outputs/thread ----------------
// lo[d] = sum_k in[2d-5+k]*w_lo[k]. Window for d0..d0+7: j in [2d0-5, 2d0+23],
// loaded as v[0..27] from base jb=2d0-8 (used: v[3..26]).
__global__ __launch_bounds__(256) void fwd_big(
    const float* __restrict__ in, float* __restrict__ lo_out,
    float* __restrict__ hi_out, int L, int sIn, int D, int sOut) {
  const int b = blockIdx.y;
  const int d0 = (blockIdx.x * 256 + threadIdx.x) * 8;
  if (d0 >= D) return;
  const float* row = in + (size_t)b * (size_t)sIn;
  const int jb = 2 * d0 - 8;
  float v[28];
  const bool interior = (jb >= 0) && (jb + 27 < L) && (d0 + 7 < D);
  if (interior) {
#pragma unroll
    for (int q = 0; q < 7; ++q) {
      float4 t = *reinterpret_cast<const float4*>(row + jb + 4 * q);
      v[4 * q + 0] = t.x; v[4 * q + 1] = t.y;
      v[4 * q + 2] = t.z; v[4 * q + 3] = t.w;
    }
  } else {
#pragma unroll
    for (int q = 0; q < 28; ++q) {
      const int j = jb + q;
      v[q] = (j >= 0 && j < L) ? row[j] : 0.f;
    }
  }
  float lo[8], hi[8];
#pragma unroll
  for (int i = 0; i < 8; ++i) {
    float a = 0.f, h = 0.f;
#pragma unroll
    for (int k = 0; k < 10; ++k) {
      const float x = v[2 * i + 3 + k];
      a += x * c_dec_lo[k];
      h += x * c_dec_hi[k];
    }
    lo[i] = a; hi[i] = h;
  }
  float* lo_row = lo_out + (size_t)b * sOut;
  float* hi_row = hi_out + (size_t)b * sOut;
  if (interior) {
    *reinterpret_cast<float4*>(lo_row + d0) = make_float4(lo[0], lo[1], lo[2], lo[3]);
    *reinterpret_cast<float4*>(lo_row + d0 + 4) = make_float4(lo[4], lo[5], lo[6], lo[7]);
    *reinterpret_cast<float4*>(hi_row + d0) = make_float4(hi[0], hi[1], hi[2], hi[3]);
    *reinterpret_cast<float4*>(hi_row + d0 + 4) = make_float4(hi[4], hi[5], hi[6], hi[7]);
  } else {
#pragma unroll
    for (int i = 0; i < 8; ++i)
      if (d0 + i < D) { lo_row[d0 + i] = lo[i]; hi_row[d0 + i] = hi[i]; }
  }
}

// ---------------- big inverse level: 16 outputs/thread ----------------
// t0 = 16g (aligned). U = t0/2-8. Both phases read window idx e+1+m:
//   acc[2e]   (t even) uses odd taps  w[2m+1]
//   acc[2e+1] (t odd)  uses even taps w[2m]
__global__ __launch_bounds__(256) void inv_big(
    const float* __restrict__ prev, const float* __restrict__ hicoef,
    const float* __restrict__ filt, int level, int L, int sIn, int Tout,
    int sOut, float* __restrict__ out) {
  const int c = blockIdx.y;
  __shared__ float4 wpack[16];  // {lo[2m], lo[2m+1], hi[2m], hi[2m+1]}
  const int tid = threadIdx.x;
  if (tid < 16) {
    const float* f = filt + ((size_t)c * 8 + level) * 64;
    wpack[tid] = make_float4(f[2 * tid], f[2 * tid + 1],
                             f[32 + 2 * tid], f[32 + 2 * tid + 1]);
  }
  __syncthreads();
  const int g = blockIdx.x * 256 + tid;
  const int t0 = 16 * g;
  if (t0 >= Tout) return;
  const int U = 8 * g - 8;
  const float* prow = prev + (size_t)c * sIn;
  const float* hrow = hicoef + (size_t)c * sIn;
  float p[24], h[24];
  const bool interior = (U >= 0) && (U + 23 < L) && (t0 + 15 < Tout);
  if (interior) {
#pragma unroll
    for (int q = 0; q < 6; ++q) {
      float4 a = *reinterpret_cast<const float4*>(prow + U + 4 * q);
      p[4 * q + 0] = a.x; p[4 * q + 1] = a.y; p[4 * q + 2] = a.z; p[4 * q + 3] = a.w;
      float4 bb = *reinterpret_cast<const float4*>(hrow + U + 4 * q);
      h[4 * q + 0] = bb.x; h[4 * q + 1] = bb.y; h[4 * q + 2] = bb.z; h[4 * q + 3] = bb.w;
    }
  } else {
#pragma unroll
    for (int q = 0; q < 24; ++q) {
      const int j = U + q;
      p[q] = (j >= 0 && j < L) ? prow[j] : 0.f;
      h[q] = (j >= 0 && j < L) ? hrow[j] : 0.f;
    }
  }
  float acc[16];
#pragma unroll
  for (int i = 0; i < 16; ++i) acc[i] = 0.f;
#pragma unroll
  for (int m = 0; m < 16; ++m) {
    const float4 w = wpack[m];
#pragma unroll
    for (int e = 0; e < 8; ++e) {
      const float pv = p[e + 1 + m], hv = h[e + 1 + m];
      acc[2 * e + 0] += pv * w.y + hv * w.w;
      acc[2 * e + 1] += pv * w.x + hv * w.z;
    }
  }
  float* orow = out + (size_t)c * sOut;
  if (interior) {
#pragma unroll
    for (int q = 0; q < 4; ++q)
      *reinterpret_cast<float4*>(orow + t0 + 4 * q) =
          make_float4(acc[4 * q], acc[4 * q + 1], acc[4 * q + 2], acc[4 * q + 3]);
  } else {
#pragma unroll
    for (int i = 0; i < 16; ++i)
      if (t0 + i < Tout) orow[t0 + i] = acc[i];
  }
}

// ---------------- fused forward levels 4..7 (one block per row) ----------------
__device__ inline void fwd_lds_level(const float* __restrict__ in,
                                     float* __restrict__ out, int L, int D,
                                     float* __restrict__ hirow, int tid) {
  for (int d = tid; d < D; d += 1024) {
    const int base = 2 * d - 5;
    float slo = 0.f, shi = 0.f;
#pragma unroll
    for (int k = 0; k < 10; ++k) {
      const int j = base + k;
      const float x = (j >= 0 && j < L) ? in[j] : 0.f;
      slo += x * c_dec_lo[k];
      shi += x * c_dec_hi[k];
    }
    out[d] = slo;
    hirow[d] = shi;
  }
}

__global__ __launch_bounds__(1024) void fwd_fused(
    const float* __restrict__ in, float* __restrict__ hi4,
    float* __restrict__ hi5, float* __restrict__ hi6,
    float* __restrict__ hi7, float* __restrict__ lo7out) {
  const int b = blockIdx.x;
  __shared__ float A[8200];
  __shared__ float Bb[4104];
  const int tid = threadIdx.x;
  const float* row = in + (size_t)b * 8196;
  for (int j = tid; j < 8193; j += 1024) A[j] = row[j];
  __syncthreads();
  fwd_lds_level(A, Bb, 8193, 4097, hi4 + (size_t)b * 4100, tid);
  __syncthreads();
  fwd_lds_level(Bb, A, 4097, 2049, hi5 + (size_t)b * 2052, tid);
  __syncthreads();
  fwd_lds_level(A, Bb, 2049, 1025, hi6 + (size_t)b * 1028, tid);
  __syncthreads();
  fwd_lds_level(Bb, A, 1025, 513, hi7 + (size_t)b * 516, tid);
  __syncthreads();
  float* lrow = lo7out + (size_t)b * 516;
  if (tid < 513) lrow[tid] = A[tid];
}

// ---------------- fused inverse levels 7..4 (one block per row) ----------------
__device__ inline void inv_lds_level(const float* __restrict__ pin,
                                     float* __restrict__ pout, int L,
                                     const float* __restrict__ hirow,
                                     const float* __restrict__ filt, int c,
                                     int level, int tid, float4* wpack) {
  __syncthreads();
  if (tid < 16) {
    const float* f = filt + ((size_t)c * 8 + level) * 64;
    wpack[tid] = make_float4(f[2 * tid], f[2 * tid + 1],
                             f[32 + 2 * tid], f[32 + 2 * tid + 1]);
  }
  __syncthreads();
  const int Tout = 2 * L - 1;
  const int t0 = 16 * tid;
  if (t0 >= Tout) return;  // no barriers below
  const int U = 8 * tid - 8;
  float p[24], h[24];
  if (U >= 0 && U + 23 < L) {
#pragma unroll
    for (int q = 0; q < 6; ++q) {
      const float4 a = *reinterpret_cast<const float4*>(pin + U + 4 * q);
      p[4 * q + 0] = a.x; p[4 * q + 1] = a.y; p[4 * q + 2] = a.z; p[4 * q + 3] = a.w;
      const float4 bb = ldz4(hirow, U + 4 * q, L);
      h[4 * q + 0] = bb.x; h[4 * q + 1] = bb.y; h[4 * q + 2] = bb.z; h[4 * q + 3] = bb.w;
    }
  } else {
#pragma unroll
    for (int q = 0; q < 24; ++q) {
      const int j = U + q;
      p[q] = (j >= 0 && j < L) ? pin[j] : 0.f;
      h[q] = (j >= 0 && j < L) ? hirow[j] : 0.f;
    }
  }
  float acc[16];
#pragma unroll
  for (int i = 0; i < 16; ++i) acc[i] = 0.f;
#pragma unroll
  for (int m = 0; m < 16; ++m) {
    const float4 w = wpack[m];
#pragma unroll
    for (int e = 0; e < 8; ++e) {
      const float pv = p[e + 1 + m], hv = h[e + 1 + m];
      acc[2 * e + 0] += pv * w.y + hv * w.w;
      acc[2 * e + 1] += pv * w.x + hv * w.z;
    }
  }
  if (t0 + 15 < Tout) {
#pragma unroll
    for (int i = 0; i < 16; ++i) pout[t0 + i] = acc[i];
  } else {
#pragma unroll
    for (int i = 0; i < 16; ++i)
      if (t0 + i < Tout) pout[t0 + i] = acc[i];
  }
}

__global__ __launch_bounds__(1024) void inv_fused(
    const float* __restrict__ lo7, const float* __restrict__ hi7,
    const float* __restrict__ hi6, const float* __restrict__ hi5,
    const float* __restrict__ hi4, const float* __restrict__ filt,
    float* __restrict__ outPrev) {
  const int c = blockIdx.x;
  __shared__ float P[8200];
  __shared__ float Q[4104];
  __shared__ float4 wpack[16];
  const int tid = threadIdx.x;
  {
    const float* l7 = lo7 + (size_t)c * 516;
    if (tid < 513) P[tid] = l7[tid];
  }
  inv_lds_level(P, Q, 513, hi7 + (size_t)c * 516, filt, c, 7, tid, wpack);
  inv_lds_level(Q, P, 1025, hi6 + (size_t)c * 1028, filt, c, 6, tid, wpack);
  inv_lds_level(P, Q, 2049, hi5 + (size_t)c * 2052, filt, c, 5, tid, wpack);
  inv_lds_level(Q, P, 4097, hi4 + (size_t)c * 4100, filt, c, 4, tid, wpack);
  __syncthreads();
  float* orow = outPrev + (size_t)c * 8196;
  for (int j = tid; j < 8193; j += 1024) orow[j] = P[j];
}

extern "C" void kernel_launch(void* const* d_in, const int* in_sizes, int n_in,
                              void* d_out, int out_size, void* d_ws,
                              size_t ws_size, hipStream_t stream) {
  const float* x = (const float*)d_in[0];
  const float* filt = (const float*)d_in[1];
  float* out = (float*)d_out;
  float* ws = (float*)d_ws;

  const int B = 128;
  const int T = 131072;
  static const int Dl[8] = {65537, 32769, 16385, 8193, 4097, 2049, 1025, 513};
  static const int PD[8] = {65540, 32772, 16388, 8196, 4100, 2052, 1028, 516};

  const size_t pingSz = (size_t)B * 65540;
  float* pp0 = ws;
  float* pp1 = ws + pingSz;
  float* hiBase = ws + 2 * pingSz;
  float* hi[8];
  size_t off = 0;
  for (int l = 0; l < 8; ++l) {
    hi[l] = hiBase + off;
    off += (size_t)B * PD[l];
  }

  auto launch_fwd = [&](const float* in, int L, int sIn, int D, int sOut,
                        float* lo, float* hv) {
    const int tpr = (D + 7) / 8;
    dim3 grid((tpr + 255) / 256, B);
    hipLaunchKernelGGL(fwd_big, grid, dim3(256), 0, stream, in, lo, hv, L, sIn,
                       D, sOut);
  };
  auto launch_inv = [&](const float* prev, const float* hv, int level, int L,
                        int sIn, int Tout, int sOut, float* dst) {
    const int tpr = (Tout + 15) / 16;
    dim3 grid((tpr + 255) / 256, B);
    hipLaunchKernelGGL(inv_big, grid, dim3(256), 0, stream, prev, hv, filt,
                       level, L, sIn, Tout, sOut, dst);
  };

  // forward levels 0..3
  launch_fwd(x, T, T, Dl[0], PD[0], pp0, hi[0]);
  launch_fwd(pp0, Dl[0], PD[0], Dl[1], PD[1], pp1, hi[1]);
  launch_fwd(pp1, Dl[1], PD[1], Dl[2], PD[2], pp0, hi[2]);
  launch_fwd(pp0, Dl[2], PD[2], Dl[3], PD[3], pp1, hi[3]);
  // fused forward levels 4..7: reads pp1 (stride 8196); lo7 -> pp0
  hipLaunchKernelGGL(fwd_fused, dim3(B), dim3(1024), 0, stream, pp1, hi[4],
                     hi[5], hi[6], hi[7], pp0);
  // fused inverse levels 7..4: lo7 in pp0 -> prev3 into pp1 (stride 8196)
  hipLaunchKernelGGL(inv_fused, dim3(B), dim3(1024), 0, stream, pp0, hi[7],
                     hi[6], hi[5], hi[4], filt, pp1);
  // inverse levels 3..0
  launch_inv(pp1, hi[3], 3, Dl[3], PD[3], Dl[2], PD[2], pp0);
  launch_inv(pp0, hi[2], 2, Dl[2], PD[2], Dl[1], PD[1], pp1);
  launch_inv(pp1, hi[1], 1, Dl[1], PD[1], Dl[0], PD[0], pp0);
  launch_inv(pp0, hi[0], 0, Dl[0], PD[0], T, T, out);
}

// Round 4
// 155.613 us; speedup vs baseline: 2.6840x; 1.3447x over previous
//
#include <hip/hip_runtime.h>

// 8-level DWT (fixed 10-tap) + 8-level per-channel IDWT (32-tap learned).
// Big levels: vectorized interior fast path, aligned float4 loads+stores.
// Small levels (fwd 4-7, inv 7-4): fused per-row kernels in LDS,
// 512 threads/block, small per-thread register windows (no scratch spills).

static __constant__ float c_dec_lo[10] = {
    0.003335725285001549f, -0.012580751999015526f, -0.006241490213011705f,
    0.07757149384006515f, -0.03224486958502952f, -0.24229488706619015f,
    0.13842814590110342f, 0.7243085284385744f, 0.6038292697974729f,
    0.160102397974125f};
static __constant__ float c_dec_hi[10] = {
    -0.160102397974125f, 0.6038292697974729f, -0.7243085284385744f,
    0.13842814590110342f, 0.24229488706619015f, -0.03224486958502952f,
    -0.07757149384006515f, -0.006241490213011705f, 0.012580751999015526f,
    0.003335725285001549f};

__device__ inline float4 ldz4(const float* __restrict__ row, int j, int L) {
  if (j >= 0 && j + 3 < L) return *reinterpret_cast<const float4*>(row + j);
  float4 r;
  r.x = (j + 0 >= 0 && j + 0 < L) ? row[j + 0] : 0.f;
  r.y = (j + 1 >= 0 && j + 1 < L) ? row[j + 1] : 0.f;
  r.z = (j + 2 >= 0 && j + 2 < L) ? row[j + 2] : 0.f;
  r.w = (j + 3 >= 0 && j + 3 < L) ? row[j + 3] : 0.f;
  return r;
}

// ---------------- big forward level: 8 outputs/thread ----------------
__global__ __launch_bounds__(256) void fwd_big(
    const float* __restrict__ in, float* __restrict__ lo_out,
    float* __restrict__ hi_out, int L, int sIn, int D, int sOut) {
  const int b = blockIdx.y;
  const int d0 = (blockIdx.x * 256 + threadIdx.x) * 8;
  if (d0 >= D) return;
  const float* row = in + (size_t)b * (size_t)sIn;
  const int jb = 2 * d0 - 8;
  float v[28];
  const bool interior = (jb >= 0) && (jb + 27 < L) && (d0 + 7 < D);
  if (interior) {
#pragma unroll
    for (int q = 0; q < 7; ++q) {
      float4 t = *reinterpret_cast<const float4*>(row + jb + 4 * q);
      v[4 * q + 0] = t.x; v[4 * q + 1] = t.y;
      v[4 * q + 2] = t.z; v[4 * q + 3] = t.w;
    }
  } else {
#pragma unroll
    for (int q = 0; q < 28; ++q) {
      const int j = jb + q;
      v[q] = (j >= 0 && j < L) ? row[j] : 0.f;
    }
  }
  float lo[8], hi[8];
#pragma unroll
  for (int i = 0; i < 8; ++i) {
    float a = 0.f, h = 0.f;
#pragma unroll
    for (int k = 0; k < 10; ++k) {
      const float x = v[2 * i + 3 + k];
      a += x * c_dec_lo[k];
      h += x * c_dec_hi[k];
    }
    lo[i] = a; hi[i] = h;
  }
  float* lo_row = lo_out + (size_t)b * sOut;
  float* hi_row = hi_out + (size_t)b * sOut;
  if (interior) {
    *reinterpret_cast<float4*>(lo_row + d0) = make_float4(lo[0], lo[1], lo[2], lo[3]);
    *reinterpret_cast<float4*>(lo_row + d0 + 4) = make_float4(lo[4], lo[5], lo[6], lo[7]);
    *reinterpret_cast<float4*>(hi_row + d0) = make_float4(hi[0], hi[1], hi[2], hi[3]);
    *reinterpret_cast<float4*>(hi_row + d0 + 4) = make_float4(hi[4], hi[5], hi[6], hi[7]);
  } else {
#pragma unroll
    for (int i = 0; i < 8; ++i)
      if (d0 + i < D) { lo_row[d0 + i] = lo[i]; hi_row[d0 + i] = hi[i]; }
  }
}

// ---------------- big inverse level: 16 outputs/thread ----------------
__global__ __launch_bounds__(256) void inv_big(
    const float* __restrict__ prev, const float* __restrict__ hicoef,
    const float* __restrict__ filt, int level, int L, int sIn, int Tout,
    int sOut, float* __restrict__ out) {
  const int c = blockIdx.y;
  __shared__ float4 wpack[16];  // {lo[2m], lo[2m+1], hi[2m], hi[2m+1]}
  const int tid = threadIdx.x;
  if (tid < 16) {
    const float* f = filt + ((size_t)c * 8 + level) * 64;
    wpack[tid] = make_float4(f[2 * tid], f[2 * tid + 1],
                             f[32 + 2 * tid], f[32 + 2 * tid + 1]);
  }
  __syncthreads();
  const int g = blockIdx.x * 256 + tid;
  const int t0 = 16 * g;
  if (t0 >= Tout) return;
  const int U = 8 * g - 8;
  const float* prow = prev + (size_t)c * sIn;
  const float* hrow = hicoef + (size_t)c * sIn;
  float p[24], h[24];
  const bool interior = (U >= 0) && (U + 23 < L) && (t0 + 15 < Tout);
  if (interior) {
#pragma unroll
    for (int q = 0; q < 6; ++q) {
      float4 a = *reinterpret_cast<const float4*>(prow + U + 4 * q);
      p[4 * q + 0] = a.x; p[4 * q + 1] = a.y; p[4 * q + 2] = a.z; p[4 * q + 3] = a.w;
      float4 bb = *reinterpret_cast<const float4*>(hrow + U + 4 * q);
      h[4 * q + 0] = bb.x; h[4 * q + 1] = bb.y; h[4 * q + 2] = bb.z; h[4 * q + 3] = bb.w;
    }
  } else {
#pragma unroll
    for (int q = 0; q < 24; ++q) {
      const int j = U + q;
      p[q] = (j >= 0 && j < L) ? prow[j] : 0.f;
      h[q] = (j >= 0 && j < L) ? hrow[j] : 0.f;
    }
  }
  float acc[16];
#pragma unroll
  for (int i = 0; i < 16; ++i) acc[i] = 0.f;
#pragma unroll
  for (int m = 0; m < 16; ++m) {
    const float4 w = wpack[m];
#pragma unroll
    for (int e = 0; e < 8; ++e) {
      const float pv = p[e + 1 + m], hv = h[e + 1 + m];
      acc[2 * e + 0] += pv * w.y + hv * w.w;
      acc[2 * e + 1] += pv * w.x + hv * w.z;
    }
  }
  float* orow = out + (size_t)c * sOut;
  if (interior) {
#pragma unroll
    for (int q = 0; q < 4; ++q)
      *reinterpret_cast<float4*>(orow + t0 + 4 * q) =
          make_float4(acc[4 * q], acc[4 * q + 1], acc[4 * q + 2], acc[4 * q + 3]);
  } else {
#pragma unroll
    for (int i = 0; i < 16; ++i)
      if (t0 + i < Tout) orow[t0 + i] = acc[i];
  }
}

// ---------------- fused forward levels 4..7 (one block per row, 512 thr) ----
// Each thread: 4 outputs per grid-stride iteration; window v[20] (idx 3..18),
// 5 aligned float4 LDS loads; float4 LDS lo-store + float4 global hi-store.
__device__ inline void fwd_tail_level(const float* __restrict__ in,
                                      float* __restrict__ out, int L, int D,
                                      float* __restrict__ hirow, int tid) {
  for (int d0 = 4 * tid; d0 < D; d0 += 4 * 512) {
    const int jb = 2 * d0 - 8;
    float v[20];
    const bool interior = (jb >= 0) && (jb + 19 < L) && (d0 + 3 < D);
    if (interior) {
#pragma unroll
      for (int q = 0; q < 5; ++q) {
        const float4 t = *reinterpret_cast<const float4*>(in + jb + 4 * q);
        v[4 * q + 0] = t.x; v[4 * q + 1] = t.y;
        v[4 * q + 2] = t.z; v[4 * q + 3] = t.w;
      }
    } else {
#pragma unroll
      for (int q = 0; q < 20; ++q) {
        const int j = jb + q;
        v[q] = (j >= 0 && j < L) ? in[j] : 0.f;
      }
    }
    float lo[4], hi[4];
#pragma unroll
    for (int i = 0; i < 4; ++i) {
      float a = 0.f, h = 0.f;
#pragma unroll
      for (int k = 0; k < 10; ++k) {
        const float x = v[2 * i + 3 + k];
        a += x * c_dec_lo[k];
        h += x * c_dec_hi[k];
      }
      lo[i] = a; hi[i] = h;
    }
    if (interior) {
      *reinterpret_cast<float4*>(out + d0) = make_float4(lo[0], lo[1], lo[2], lo[3]);
      *reinterpret_cast<float4*>(hirow + d0) = make_float4(hi[0], hi[1], hi[2], hi[3]);
    } else {
#pragma unroll
      for (int i = 0; i < 4; ++i)
        if (d0 + i < D) { out[d0 + i] = lo[i]; hirow[d0 + i] = hi[i]; }
    }
  }
}

__global__ __launch_bounds__(512) void fwd_fused(
    const float* __restrict__ in, float* __restrict__ hi4,
    float* __restrict__ hi5, float* __restrict__ hi6,
    float* __restrict__ hi7, float* __restrict__ lo7out) {
  const int b = blockIdx.x;
  __shared__ float A[8200];
  __shared__ float Bb[4104];
  const int tid = threadIdx.x;
  const float* row = in + (size_t)b * 8196;
  for (int j4 = tid; j4 < 2048; j4 += 512)
    *reinterpret_cast<float4*>(A + 4 * j4) =
        *reinterpret_cast<const float4*>(row + 4 * j4);
  if (tid == 0) A[8192] = row[8192];
  __syncthreads();
  fwd_tail_level(A, Bb, 8193, 4097, hi4 + (size_t)b * 4100, tid);
  __syncthreads();
  fwd_tail_level(Bb, A, 4097, 2049, hi5 + (size_t)b * 2052, tid);
  __syncthreads();
  fwd_tail_level(A, Bb, 2049, 1025, hi6 + (size_t)b * 1028, tid);
  __syncthreads();
  fwd_tail_level(Bb, A, 1025, 513, hi7 + (size_t)b * 516, tid);
  __syncthreads();
  float* lrow = lo7out + (size_t)b * 516;
  for (int j4 = tid; j4 < 128; j4 += 512)
    *reinterpret_cast<float4*>(lrow + 4 * j4) =
        *reinterpret_cast<const float4*>(A + 4 * j4);
  if (tid == 0) lrow[512] = A[512];
}

// ---------------- fused inverse levels 7..4 (one block per row, 512 thr) ----
// Each thread: 8 outputs (t0 = 8g) per grid-stride iteration.
//   even i: acc[i] = sum_m p[i/2+1+m]*wlo[2m+1] + h[..]*whi[2m+1]
//   odd  i: acc[i] = sum_m p[(i+1)/2+m]*wlo[2m] + h[..]*whi[2m]
// window p[0..19], U = t0/2 - 8 (multiple of 4).
__device__ inline void inv_tail_level(const float* __restrict__ pin,
                                      float* __restrict__ pout, int L,
                                      const float* __restrict__ hirow,
                                      const float* __restrict__ filt, int c,
                                      int level, int tid, float4* wpack) {
  __syncthreads();
  if (tid < 16) {
    const float* f = filt + ((size_t)c * 8 + level) * 64;
    wpack[tid] = make_float4(f[2 * tid], f[2 * tid + 1],
                             f[32 + 2 * tid], f[32 + 2 * tid + 1]);
  }
  __syncthreads();
  const int Tout = 2 * L - 1;
  for (int t0 = 8 * tid; t0 < Tout; t0 += 8 * 512) {
    const int U = t0 / 2 - 8;
    float p[20], h[20];
    if (U >= 0 && U + 19 < L) {
#pragma unroll
      for (int q = 0; q < 5; ++q) {
        const float4 a = *reinterpret_cast<const float4*>(pin + U + 4 * q);
        p[4 * q + 0] = a.x; p[4 * q + 1] = a.y; p[4 * q + 2] = a.z; p[4 * q + 3] = a.w;
        const float4 bb = *reinterpret_cast<const float4*>(hirow + U + 4 * q);
        h[4 * q + 0] = bb.x; h[4 * q + 1] = bb.y; h[4 * q + 2] = bb.z; h[4 * q + 3] = bb.w;
      }
    } else {
#pragma unroll
      for (int q = 0; q < 20; ++q) {
        const int j = U + q;
        p[q] = (j >= 0 && j < L) ? pin[j] : 0.f;
        h[q] = (j >= 0 && j < L) ? hirow[j] : 0.f;
      }
    }
    float acc[8];
#pragma unroll
    for (int i = 0; i < 8; ++i) acc[i] = 0.f;
#pragma unroll
    for (int m = 0; m < 16; ++m) {
      const float4 w = wpack[m];
#pragma unroll
      for (int e = 0; e < 4; ++e) {
        const float pe = p[e + 1 + m], he = h[e + 1 + m];
        acc[2 * e + 0] += pe * w.y + he * w.w;
        acc[2 * e + 1] += pe * w.x + he * w.z;
      }
    }
    if (t0 + 7 < Tout) {
      *reinterpret_cast<float4*>(pout + t0) =
          make_float4(acc[0], acc[1], acc[2], acc[3]);
      *reinterpret_cast<float4*>(pout + t0 + 4) =
          make_float4(acc[4], acc[5], acc[6], acc[7]);
    } else {
#pragma unroll
      for (int i = 0; i < 8; ++i)
        if (t0 + i < Tout) pout[t0 + i] = acc[i];
    }
  }
}

__global__ __launch_bounds__(512) void inv_fused(
    const float* __restrict__ lo7, const float* __restrict__ hi7,
    const float* __restrict__ hi6, const float* __restrict__ hi5,
    const float* __restrict__ hi4, const float* __restrict__ filt,
    float* __restrict__ outPrev) {
  const int c = blockIdx.x;
  __shared__ float P[8200];
  __shared__ float Q[4104];
  __shared__ float4 wpack[16];
  const int tid = threadIdx.x;
  {
    const float* l7 = lo7 + (size_t)c * 516;
    for (int j4 = tid; j4 < 128; j4 += 512)
      *reinterpret_cast<float4*>(P + 4 * j4) =
          *reinterpret_cast<const float4*>(l7 + 4 * j4);
    if (tid == 0) P[512] = l7[512];
  }
  inv_tail_level(P, Q, 513, hi7 + (size_t)c * 516, filt, c, 7, tid, wpack);
  inv_tail_level(Q, P, 1025, hi6 + (size_t)c * 1028, filt, c, 6, tid, wpack);
  inv_tail_level(P, Q, 2049, hi5 + (size_t)c * 2052, filt, c, 5, tid, wpack);
  inv_tail_level(Q, P, 4097, hi4 + (size_t)c * 4100, filt, c, 4, tid, wpack);
  __syncthreads();
  float* orow = outPrev + (size_t)c * 8196;
  for (int j4 = tid; j4 < 2048; j4 += 512)
    *reinterpret_cast<float4*>(orow + 4 * j4) =
        *reinterpret_cast<const float4*>(P + 4 * j4);
  if (tid == 0) orow[8192] = P[8192];
}

extern "C" void kernel_launch(void* const* d_in, const int* in_sizes, int n_in,
                              void* d_out, int out_size, void* d_ws,
                              size_t ws_size, hipStream_t stream) {
  const float* x = (const float*)d_in[0];
  const float* filt = (const float*)d_in[1];
  float* out = (float*)d_out;
  float* ws = (float*)d_ws;

  const int B = 128;
  const int T = 131072;
  static const int Dl[8] = {65537, 32769, 16385, 8193, 4097, 2049, 1025, 513};
  static const int PD[8] = {65540, 32772, 16388, 8196, 4100, 2052, 1028, 516};

  const size_t pingSz = (size_t)B * 65540;
  float* pp0 = ws;
  float* pp1 = ws + pingSz;
  float* hiBase = ws + 2 * pingSz;
  float* hi[8];
  size_t off = 0;
  for (int l = 0; l < 8; ++l) {
    hi[l] = hiBase + off;
    off += (size_t)B * PD[l];
  }

  auto launch_fwd = [&](const float* in, int L, int sIn, int D, int sOut,
                        float* lo, float* hv) {
    const int tpr = (D + 7) / 8;
    dim3 grid((tpr + 255) / 256, B);
    hipLaunchKernelGGL(fwd_big, grid, dim3(256), 0, stream, in, lo, hv, L, sIn,
                       D, sOut);
  };
  auto launch_inv = [&](const float* prev, const float* hv, int level, int L,
                        int sIn, int Tout, int sOut, float* dst) {
    const int tpr = (Tout + 15) / 16;
    dim3 grid((tpr + 255) / 256, B);
    hipLaunchKernelGGL(inv_big, grid, dim3(256), 0, stream, prev, hv, filt,
                       level, L, sIn, Tout, sOut, dst);
  };

  // forward levels 0..3
  launch_fwd(x, T, T, Dl[0], PD[0], pp0, hi[0]);
  launch_fwd(pp0, Dl[0], PD[0], Dl[1], PD[1], pp1, hi[1]);
  launch_fwd(pp1, Dl[1], PD[1], Dl[2], PD[2], pp0, hi[2]);
  launch_fwd(pp0, Dl[2], PD[2], Dl[3], PD[3], pp1, hi[3]);
  // fused forward levels 4..7: reads pp1 (stride 8196); lo7 -> pp0
  hipLaunchKernelGGL(fwd_fused, dim3(B), dim3(512), 0, stream, pp1, hi[4],
                     hi[5], hi[6], hi[7], pp0);
  // fused inverse levels 7..4: lo7 in pp0 -> prev3 into pp1 (stride 8196)
  hipLaunchKernelGGL(inv_fused, dim3(B), dim3(512), 0, stream, pp0, hi[7],
                     hi[6], hi[5], hi[4], filt, pp1);
  // inverse levels 3..0
  launch_inv(pp1, hi[3], 3, Dl[3], PD[3], Dl[2], PD[2], pp0);
  launch_inv(pp0, hi[2], 2, Dl[2], PD[2], Dl[1], PD[1], pp1);
  launch_inv(pp1, hi[1], 1, Dl[1], PD[1], Dl[0], PD[0], pp0);
  launch_inv(pp0, hi[0], 0, Dl[0], PD[0], T, T, out);
}

// Round 5
// 153.364 us; speedup vs baseline: 2.7234x; 1.0147x over previous
//
#include <hip/hip_runtime.h>

// 8-level DWT + 8-level per-channel IDWT in 3 kernels:
//  fwd03: levels 0-3 halo-fused per 1024-wide lo3 tile (x -> hi0..hi3, lo3)
//  mid_fused: fwd levels 4-7 + inv levels 7-4 per row, hi4..7 LDS-only
//  inv03: inv levels 3-0 halo-fused per 16384-wide out tile

static __constant__ float c_dec_lo[10] = {
    0.003335725285001549f, -0.012580751999015526f, -0.006241490213011705f,
    0.07757149384006515f, -0.03224486958502952f, -0.24229488706619015f,
    0.13842814590110342f, 0.7243085284385744f, 0.6038292697974729f,
    0.160102397974125f};
static __constant__ float c_dec_hi[10] = {
    -0.160102397974125f, 0.6038292697974729f, -0.7243085284385744f,
    0.13842814590110342f, 0.24229488706619015f, -0.03224486958502952f,
    -0.07757149384006515f, -0.006241490213011705f, 0.012580751999015526f,
    0.003335725285001549f};

__device__ inline float4 ldz4(const float* __restrict__ row, int j, int L) {
  if (j >= 0 && j + 3 < L) return *reinterpret_cast<const float4*>(row + j);
  float4 r;
  r.x = (j + 0 >= 0 && j + 0 < L) ? row[j + 0] : 0.f;
  r.y = (j + 1 >= 0 && j + 1 < L) ? row[j + 1] : 0.f;
  r.z = (j + 2 >= 0 && j + 2 < L) ? row[j + 2] : 0.f;
  r.w = (j + 3 >= 0 && j + 3 < L) ? row[j + 3] : 0.f;
  return r;
}

__device__ inline void load20(const float* src, int base, float* v) {
#pragma unroll
  for (int q = 0; q < 5; ++q) {
    const float4 t = *reinterpret_cast<const float4*>(src + base + 4 * q);
    v[4 * q + 0] = t.x; v[4 * q + 1] = t.y;
    v[4 * q + 2] = t.z; v[4 * q + 3] = t.w;
  }
}

__device__ inline void fir10x2(const float* v, float* lo, float* hv) {
#pragma unroll
  for (int i = 0; i < 4; ++i) {
    float a = 0.f, h = 0.f;
#pragma unroll
    for (int k = 0; k < 10; ++k) {
      const float xx = v[2 * i + 3 + k];
      a += xx * c_dec_lo[k];
      h += xx * c_dec_hi[k];
    }
    lo[i] = a; hv[i] = h;
  }
}

// Store quad into LDS window with zero-pad outside valid rel range [vlo, vhi).
__device__ inline void store_pad(float* S, int idx, const float* lo, int vlo,
                                 int vhi) {
  if (idx >= vlo && idx + 3 < vhi) {
    *reinterpret_cast<float4*>(S + idx) =
        make_float4(lo[0], lo[1], lo[2], lo[3]);
  } else {
#pragma unroll
    for (int i = 0; i < 4; ++i)
      S[idx + i] = (idx + i >= vlo && idx + i < vhi) ? lo[i] : 0.f;
  }
}

// Write quad of hi to global (abs base A+idx) for rel range [es, ee).
__device__ inline void store_hi(float* hg, int A, int idx, const float* hv,
                                int es, int ee) {
  if (idx >= es && idx + 3 < ee) {
    *reinterpret_cast<float4*>(hg + A + idx) =
        make_float4(hv[0], hv[1], hv[2], hv[3]);
  } else {
#pragma unroll
    for (int i = 0; i < 4; ++i)
      if (idx + i >= es && idx + i < ee) hg[A + idx + i] = hv[i];
  }
}

// ---------------- fwd levels 0-3 fused ----------------
// Tile: 1024 lo3 outputs. Windows: lo0 8276 @ A0=8b3-56, lo1 4132 @ A1=4b3-24,
// lo2 2060 @ A2=2b3-8. All LDS reads land at rel = 2*idx (A_{l-1} = 2*A_l - 8).
__global__ __launch_bounds__(512) void fwd03(
    const float* __restrict__ x, float* __restrict__ hi0,
    float* __restrict__ hi1, float* __restrict__ hi2,
    float* __restrict__ hi3, float* __restrict__ lo3) {
  const int b = blockIdx.y;
  const int b3 = blockIdx.x * 1024;
  __shared__ float S0[8276];
  __shared__ float S1[4132];
  const int tid = threadIdx.x;

  {  // level 0: x -> S0 (lo0), hi0 exclusive [8b3, 8b3+8192)
    const float* xr = x + (size_t)b * 131072;
    float* h0 = hi0 + (size_t)b * 65540;
    const int A0 = 8 * b3 - 56;
    const int vlo = -A0, vhi = 65537 - A0;
    const int ee = min(8248, vhi);
    const int xoff = 16 * b3 - 120;
    for (int idx = 4 * tid; idx < 8276; idx += 2048) {
      const int jb = 2 * idx + xoff;
      float v[20];
#pragma unroll
      for (int q = 0; q < 5; ++q) {
        const float4 t = ldz4(xr, jb + 4 * q, 131072);
        v[4 * q + 0] = t.x; v[4 * q + 1] = t.y;
        v[4 * q + 2] = t.z; v[4 * q + 3] = t.w;
      }
      float lo[4], hv[4];
      fir10x2(v, lo, hv);
      store_pad(S0, idx, lo, vlo, vhi);
      store_hi(h0, A0, idx, hv, 56, ee);
    }
  }
  __syncthreads();
  {  // level 1: S0 -> S1 (lo1), hi1 exclusive [4b3, 4b3+4096)
    float* h1 = hi1 + (size_t)b * 32772;
    const int A1 = 4 * b3 - 24;
    const int vlo = -A1, vhi = 32769 - A1;
    const int ee = min(4120, vhi);
    for (int idx = 4 * tid; idx < 4132; idx += 2048) {
      float v[20];
      load20(S0, 2 * idx, v);
      float lo[4], hv[4];
      fir10x2(v, lo, hv);
      store_pad(S1, idx, lo, vlo, vhi);
      store_hi(h1, A1, idx, hv, 24, ee);
    }
  }
  __syncthreads();
  {  // level 2: S1 -> S0 (lo2, reuse), hi2 exclusive [2b3, 2b3+2048)
    float* h2 = hi2 + (size_t)b * 16388;
    const int A2 = 2 * b3 - 8;
    const int vlo = -A2, vhi = 16385 - A2;
    const int ee = min(2056, vhi);
    for (int idx = 4 * tid; idx < 2060; idx += 2048) {
      float v[20];
      load20(S1, 2 * idx, v);
      float lo[4], hv[4];
      fir10x2(v, lo, hv);
      store_pad(S0, idx, lo, vlo, vhi);
      store_hi(h2, A2, idx, hv, 8, ee);
    }
  }
  __syncthreads();
  {  // level 3: S0 -> global lo3 + hi3, range [b3, b3+ne3)
    float* l3 = lo3 + (size_t)b * 8196;
    float* h3 = hi3 + (size_t)b * 8196;
    const int ne3 = min(1024, 8193 - b3);
    for (int idx = 4 * tid; idx < 1024; idx += 2048) {
      float v[20];
      load20(S0, 2 * idx, v);
      float lo[4], hv[4];
      fir10x2(v, lo, hv);
      store_hi(l3, b3, idx, lo, 0, ne3);
      store_hi(h3, b3, idx, hv, 0, ne3);
    }
  }
}

// ---------------- inverse level primitive ----------------
// 8 outputs per thread-group step; outputs o (rel), t = Aout + o.
//   acc[2e]   (even t-offset) uses odd taps  w[2m+1] (w.y / w.w)
//   acc[2e+1] uses even taps w[2m] (w.x / w.z)
// p window Sprev[o/2 + reloff .. +19]; h window global hig[U0 + o/2 ..].
__device__ inline void inv_accum(const float* p, const float* h,
                                 const float4* wpk, float* acc) {
#pragma unroll
  for (int i = 0; i < 8; ++i) acc[i] = 0.f;
#pragma unroll
  for (int m = 0; m < 16; ++m) {
    const float4 w = wpk[m];
#pragma unroll
    for (int e = 0; e < 4; ++e) {
      const float pe = p[e + 1 + m], he = h[e + 1 + m];
      acc[2 * e + 0] += pe * w.y + he * w.w;
      acc[2 * e + 1] += pe * w.x + he * w.z;
    }
  }
}

__device__ inline void inv_store_pad(float* S, int o, const float* acc,
                                     int vlo, int vhi) {
  if (o >= vlo && o + 7 < vhi) {
    *reinterpret_cast<float4*>(S + o) =
        make_float4(acc[0], acc[1], acc[2], acc[3]);
    *reinterpret_cast<float4*>(S + o + 4) =
        make_float4(acc[4], acc[5], acc[6], acc[7]);
  } else {
#pragma unroll
    for (int i = 0; i < 8; ++i)
      S[o + i] = (o + i >= vlo && o + i < vhi) ? acc[i] : 0.f;
  }
}

__device__ inline void inv_stage_lds(const float* Sprev, int reloff,
                                     const float* __restrict__ hig, int Dhi,
                                     int U0, float* Sout, int NOUT, int Aout,
                                     int lenOut, const float4* wpk, int tid) {
  const int vlo = -Aout, vhi = lenOut - Aout;
  for (int o = 8 * tid; o < NOUT; o += 4096) {
    const int rel = (o >> 1) + reloff;
    float p[20], h[20];
#pragma unroll
    for (int q = 0; q < 5; ++q) {
      const float4 a = *reinterpret_cast<const float4*>(Sprev + rel + 4 * q);
      p[4 * q + 0] = a.x; p[4 * q + 1] = a.y;
      p[4 * q + 2] = a.z; p[4 * q + 3] = a.w;
      const float4 bb = ldz4(hig, U0 + (o >> 1) + 4 * q, Dhi);
      h[4 * q + 0] = bb.x; h[4 * q + 1] = bb.y;
      h[4 * q + 2] = bb.z; h[4 * q + 3] = bb.w;
    }
    float acc[8];
    inv_accum(p, h, wpk, acc);
    inv_store_pad(Sout, o, acc, vlo, vhi);
  }
}

__device__ inline void inv_stage_glb(const float* __restrict__ pg, int Dp,
                                     int P0, const float* __restrict__ hig,
                                     int Dhi, int U0, float* Sout, int NOUT,
                                     int Aout, int lenOut, const float4* wpk,
                                     int tid) {
  const int vlo = -Aout, vhi = lenOut - Aout;
  for (int o = 8 * tid; o < NOUT; o += 4096) {
    float p[20], h[20];
#pragma unroll
    for (int q = 0; q < 5; ++q) {
      const float4 a = ldz4(pg, P0 + (o >> 1) + 4 * q, Dp);
      p[4 * q + 0] = a.x; p[4 * q + 1] = a.y;
      p[4 * q + 2] = a.z; p[4 * q + 3] = a.w;
      const float4 bb = ldz4(hig, U0 + (o >> 1) + 4 * q, Dhi);
      h[4 * q + 0] = bb.x; h[4 * q + 1] = bb.y;
      h[4 * q + 2] = bb.z; h[4 * q + 3] = bb.w;
    }
    float acc[8];
    inv_accum(p, h, wpk, acc);
    inv_store_pad(Sout, o, acc, vlo, vhi);
  }
}

__device__ inline void inv_stage_out(const float* Sprev,
                                     const float* __restrict__ hig, int Dhi,
                                     int U0, float* __restrict__ og,
                                     const float4* wpk, int tid) {
  for (int o = 8 * tid; o < 16384; o += 4096) {
    const int rel = o >> 1;
    float p[20], h[20];
#pragma unroll
    for (int q = 0; q < 5; ++q) {
      const float4 a = *reinterpret_cast<const float4*>(Sprev + rel + 4 * q);
      p[4 * q + 0] = a.x; p[4 * q + 1] = a.y;
      p[4 * q + 2] = a.z; p[4 * q + 3] = a.w;
      const float4 bb = ldz4(hig, U0 + (o >> 1) + 4 * q, Dhi);
      h[4 * q + 0] = bb.x; h[4 * q + 1] = bb.y;
      h[4 * q + 2] = bb.z; h[4 * q + 3] = bb.w;
    }
    float acc[8];
    inv_accum(p, h, wpk, acc);
    *reinterpret_cast<float4*>(og + o) =
        make_float4(acc[0], acc[1], acc[2], acc[3]);
    *reinterpret_cast<float4*>(og + o + 4) =
        make_float4(acc[4], acc[5], acc[6], acc[7]);
  }
}

// ---------------- inv levels 3-0 fused ----------------
// Tile: 16384 outputs @ t0b. prev0 8208 @ t0b/2-8 (X), prev1 4128 @ t0b/4-16
// (Y), prev2 2080 @ t0b/8-16 (X first), prev3/hi from global.
__global__ __launch_bounds__(512) void inv03(
    const float* __restrict__ prev3, const float* __restrict__ hi3,
    const float* __restrict__ hi2, const float* __restrict__ hi1,
    const float* __restrict__ hi0, const float* __restrict__ filt,
    float* __restrict__ out) {
  const int c = blockIdx.y;
  const int t0b = blockIdx.x * 16384;
  __shared__ float X[8208];
  __shared__ float Y[4128];
  __shared__ float4 wp[64];  // [0:16) lvl3, [16:32) lvl2, [32:48) lvl1, [48:64) lvl0
  const int tid = threadIdx.x;
  if (tid < 64) {
    const int lvl = tid >> 4, m = tid & 15;
    const float* f = filt + ((size_t)c * 8 + (3 - lvl)) * 64;
    wp[tid] = make_float4(f[2 * m], f[2 * m + 1], f[32 + 2 * m],
                          f[32 + 2 * m + 1]);
  }
  __syncthreads();
  const float* p3 = prev3 + (size_t)c * 8196;
  const float* h3 = hi3 + (size_t)c * 8196;
  const float* h2 = hi2 + (size_t)c * 16388;
  const float* h1 = hi1 + (size_t)c * 32772;
  const float* h0 = hi0 + (size_t)c * 65540;
  // stage: prev3,hi3 -> prev2 (X)
  inv_stage_glb(p3, 8193, t0b / 16 - 16, h3, 8193, t0b / 16 - 16, X, 2080,
                t0b / 8 - 16, 16385, wp, tid);
  __syncthreads();
  // stage: prev2 (X), hi2 -> prev1 (Y)
  inv_stage_lds(X, 0, h2, 16385, t0b / 8 - 16, Y, 4128, t0b / 4 - 16, 32769,
                wp + 16, tid);
  __syncthreads();
  // stage: prev1 (Y), hi1 -> prev0 (X)
  inv_stage_lds(Y, 4, h1, 32769, t0b / 4 - 12, X, 8208, t0b / 2 - 8, 65537,
                wp + 32, tid);
  __syncthreads();
  // stage: prev0 (X), hi0 -> out tile
  inv_stage_out(X, h0, 65537, t0b / 2 - 8, out + (size_t)c * 131072 + t0b,
                wp + 48, tid);
}

// ---------------- middle: fwd 4-7 + inv 7-4, one block per row ----------------
__device__ inline void fwd_tail_level(const float* __restrict__ in,
                                      float* __restrict__ outp, int L, int D,
                                      float* __restrict__ hirow, int tid) {
  for (int d0 = 4 * tid; d0 < D; d0 += 2048) {
    const int jb = 2 * d0 - 8;
    float v[20];
    const bool interior = (jb >= 0) && (jb + 19 < L) && (d0 + 3 < D);
    if (interior) {
#pragma unroll
      for (int q = 0; q < 5; ++q) {
        const float4 t = *reinterpret_cast<const float4*>(in + jb + 4 * q);
        v[4 * q + 0] = t.x; v[4 * q + 1] = t.y;
        v[4 * q + 2] = t.z; v[4 * q + 3] = t.w;
      }
    } else {
#pragma unroll
      for (int q = 0; q < 20; ++q) {
        const int j = jb + q;
        v[q] = (j >= 0 && j < L) ? in[j] : 0.f;
      }
    }
    float lo[4], hv[4];
    fir10x2(v, lo, hv);
    if (interior) {
      *reinterpret_cast<float4*>(outp + d0) =
          make_float4(lo[0], lo[1], lo[2], lo[3]);
      *reinterpret_cast<float4*>(hirow + d0) =
          make_float4(hv[0], hv[1], hv[2], hv[3]);
    } else {
#pragma unroll
      for (int i = 0; i < 4; ++i)
        if (d0 + i < D) { outp[d0 + i] = lo[i]; hirow[d0 + i] = hv[i]; }
    }
  }
}

__device__ inline void inv_tail_level(const float* __restrict__ pin,
                                      float* __restrict__ pout, int L,
                                      const float* __restrict__ hirow,
                                      const float* __restrict__ filt, int c,
                                      int level, int tid, float4* wpack) {
  __syncthreads();
  if (tid < 16) {
    const float* f = filt + ((size_t)c * 8 + level) * 64;
    wpack[tid] = make_float4(f[2 * tid], f[2 * tid + 1], f[32 + 2 * tid],
                             f[32 + 2 * tid + 1]);
  }
  __syncthreads();
  const int Tout = 2 * L - 1;
  for (int t0 = 8 * tid; t0 < Tout; t0 += 4096) {
    const int U = t0 / 2 - 8;
    float p[20], h[20];
    if (U >= 0 && U + 19 < L) {
#pragma unroll
      for (int q = 0; q < 5; ++q) {
        const float4 a = *reinterpret_cast<const float4*>(pin + U + 4 * q);
        p[4 * q + 0] = a.x; p[4 * q + 1] = a.y;
        p[4 * q + 2] = a.z; p[4 * q + 3] = a.w;
        const float4 bb = *reinterpret_cast<const float4*>(hirow + U + 4 * q);
        h[4 * q + 0] = bb.x; h[4 * q + 1] = bb.y;
        h[4 * q + 2] = bb.z; h[4 * q + 3] = bb.w;
      }
    } else {
#pragma unroll
      for (int q = 0; q < 20; ++q) {
        const int j = U + q;
        p[q] = (j >= 0 && j < L) ? pin[j] : 0.f;
        h[q] = (j >= 0 && j < L) ? hirow[j] : 0.f;
      }
    }
    float acc[8];
    inv_accum(p, h, wpack, acc);
    if (t0 + 7 < Tout) {
      *reinterpret_cast<float4*>(pout + t0) =
          make_float4(acc[0], acc[1], acc[2], acc[3]);
      *reinterpret_cast<float4*>(pout + t0 + 4) =
          make_float4(acc[4], acc[5], acc[6], acc[7]);
    } else {
#pragma unroll
      for (int i = 0; i < 8; ++i)
        if (t0 + i < Tout) pout[t0 + i] = acc[i];
    }
  }
}

__global__ __launch_bounds__(512) void mid_fused(
    const float* __restrict__ lo3, const float* __restrict__ filt,
    float* __restrict__ prev3out) {
  const int b = blockIdx.x;
  __shared__ float A[8200];
  __shared__ float Bb[4104];
  __shared__ float H4[4100];
  __shared__ float H5[2052];
  __shared__ float H6[1028];
  __shared__ float H7[516];
  __shared__ float4 wpack[16];
  const int tid = threadIdx.x;
  const float* row = lo3 + (size_t)b * 8196;
  for (int j4 = tid; j4 < 2048; j4 += 512)
    *reinterpret_cast<float4*>(A + 4 * j4) =
        *reinterpret_cast<const float4*>(row + 4 * j4);
  if (tid == 0) A[8192] = row[8192];
  __syncthreads();
  fwd_tail_level(A, Bb, 8193, 4097, H4, tid);
  __syncthreads();
  fwd_tail_level(Bb, A, 4097, 2049, H5, tid);
  __syncthreads();
  fwd_tail_level(A, Bb, 2049, 1025, H6, tid);
  __syncthreads();
  fwd_tail_level(Bb, A, 1025, 513, H7, tid);
  // inverse (inv_tail_level starts with its own __syncthreads)
  inv_tail_level(A, Bb, 513, H7, filt, b, 7, tid, wpack);
  inv_tail_level(Bb, A, 1025, H6, filt, b, 6, tid, wpack);
  inv_tail_level(A, Bb, 2049, H5, filt, b, 5, tid, wpack);
  inv_tail_level(Bb, prev3out + (size_t)b * 8196, 4097, H4, filt, b, 4, tid,
                 wpack);
}

extern "C" void kernel_launch(void* const* d_in, const int* in_sizes, int n_in,
                              void* d_out, int out_size, void* d_ws,
                              size_t ws_size, hipStream_t stream) {
  const float* x = (const float*)d_in[0];
  const float* filt = (const float*)d_in[1];
  float* out = (float*)d_out;
  float* ws = (float*)d_ws;

  const int B = 128;
  float* lo3buf = ws;
  float* prev3buf = lo3buf + (size_t)B * 8196;
  float* hi0 = prev3buf + (size_t)B * 8196;
  float* hi1 = hi0 + (size_t)B * 65540;
  float* hi2 = hi1 + (size_t)B * 32772;
  float* hi3 = hi2 + (size_t)B * 16388;

  hipLaunchKernelGGL(fwd03, dim3(9, B), dim3(512), 0, stream, x, hi0, hi1, hi2,
                     hi3, lo3buf);
  hipLaunchKernelGGL(mid_fused, dim3(B), dim3(512), 0, stream, lo3buf, filt,
                     prev3buf);
  hipLaunchKernelGGL(inv03, dim3(8, B), dim3(512), 0, stream, prev3buf, hi3,
                     hi2, hi1, hi0, filt, out);
}

// Round 6
// 149.746 us; speedup vs baseline: 2.7892x; 1.0242x over previous
//
#include <hip/hip_runtime.h>

// 8-level DWT + 8-level per-channel IDWT in 3 kernels.
//  fwd03: levels 0-3 halo-fused per 512-wide lo3 tile, 256 thr, ~25KB LDS
//  mid_fused: fwd 4-7 + inv 7-4 per row (unchanged from r5)
//  inv03: inv levels 3-0 halo-fused per 8192-wide out tile, 256 thr, ~26KB LDS
// Interior blocks (1<=bx<=14) take a guard-free straight-line path.

static __constant__ float c_dec_lo[10] = {
    0.003335725285001549f, -0.012580751999015526f, -0.006241490213011705f,
    0.07757149384006515f, -0.03224486958502952f, -0.24229488706619015f,
    0.13842814590110342f, 0.7243085284385744f, 0.6038292697974729f,
    0.160102397974125f};
static __constant__ float c_dec_hi[10] = {
    -0.160102397974125f, 0.6038292697974729f, -0.7243085284385744f,
    0.13842814590110342f, 0.24229488706619015f, -0.03224486958502952f,
    -0.07757149384006515f, -0.006241490213011705f, 0.012580751999015526f,
    0.003335725285001549f};

__device__ inline float4 ldz4(const float* __restrict__ row, int j, int L) {
  if (j >= 0 && j + 3 < L) return *reinterpret_cast<const float4*>(row + j);
  float4 r;
  r.x = (j + 0 >= 0 && j + 0 < L) ? row[j + 0] : 0.f;
  r.y = (j + 1 >= 0 && j + 1 < L) ? row[j + 1] : 0.f;
  r.z = (j + 2 >= 0 && j + 2 < L) ? row[j + 2] : 0.f;
  r.w = (j + 3 >= 0 && j + 3 < L) ? row[j + 3] : 0.f;
  return r;
}

__device__ inline void load20(const float* src, int base, float* v) {
#pragma unroll
  for (int q = 0; q < 5; ++q) {
    const float4 t = *reinterpret_cast<const float4*>(src + base + 4 * q);
    v[4 * q + 0] = t.x; v[4 * q + 1] = t.y;
    v[4 * q + 2] = t.z; v[4 * q + 3] = t.w;
  }
}

__device__ inline void load20z(const float* __restrict__ src, int base, int L,
                               float* v) {
#pragma unroll
  for (int q = 0; q < 5; ++q) {
    const float4 t = ldz4(src, base + 4 * q, L);
    v[4 * q + 0] = t.x; v[4 * q + 1] = t.y;
    v[4 * q + 2] = t.z; v[4 * q + 3] = t.w;
  }
}

__device__ inline void fir10x2(const float* v, float* lo, float* hv) {
#pragma unroll
  for (int i = 0; i < 4; ++i) {
    float a = 0.f, h = 0.f;
#pragma unroll
    for (int k = 0; k < 10; ++k) {
      const float xx = v[2 * i + 3 + k];
      a += xx * c_dec_lo[k];
      h += xx * c_dec_hi[k];
    }
    lo[i] = a; hv[i] = h;
  }
}

__device__ inline void store_pad(float* S, int idx, const float* lo, int vlo,
                                 int vhi) {
  if (idx >= vlo && idx + 3 < vhi) {
    *reinterpret_cast<float4*>(S + idx) =
        make_float4(lo[0], lo[1], lo[2], lo[3]);
  } else {
#pragma unroll
    for (int i = 0; i < 4; ++i)
      S[idx + i] = (idx + i >= vlo && idx + i < vhi) ? lo[i] : 0.f;
  }
}

__device__ inline void store_hi(float* hg, int A, int idx, const float* hv,
                                int es, int ee) {
  if (idx >= es && idx + 3 < ee) {
    *reinterpret_cast<float4*>(hg + A + idx) =
        make_float4(hv[0], hv[1], hv[2], hv[3]);
  } else {
#pragma unroll
    for (int i = 0; i < 4; ++i)
      if (idx + i >= es && idx + i < ee) hg[A + idx + i] = hv[i];
  }
}

__device__ inline void st4(float* dst, const float* a) {
  *reinterpret_cast<float4*>(dst) = make_float4(a[0], a[1], a[2], a[3]);
}

// ---------------- fwd levels 0-3 fused, tile 512, 256 threads ----------------
// S0 4180 @ A0=8b3-56, S1 2084 @ A1=4b3-24, lo2 1036 @ A2=2b3-8 (in S0).
__global__ __launch_bounds__(256) void fwd03(
    const float* __restrict__ x, float* __restrict__ hi0,
    float* __restrict__ hi1, float* __restrict__ hi2,
    float* __restrict__ hi3, float* __restrict__ lo3) {
  const int b = blockIdx.y;
  const int bx = blockIdx.x;
  const int b3 = bx * 512;
  __shared__ float S0[4180];
  __shared__ float S1[2084];
  const int tid = threadIdx.x;
  const bool fast = (bx >= 1) && (bx <= 14);
  const float* xr = x + (size_t)b * 131072;
  float* h0 = hi0 + (size_t)b * 65540;
  float* h1 = hi1 + (size_t)b * 32772;
  float* h2 = hi2 + (size_t)b * 16388;
  float* h3 = hi3 + (size_t)b * 8196;
  float* l3 = lo3 + (size_t)b * 8196;
  const int A0 = 8 * b3 - 56, A1 = 4 * b3 - 24, A2 = 2 * b3 - 8;
  const int xoff = 2 * A0 - 8;

  if (fast) {
    for (int idx = 4 * tid; idx < 4180; idx += 1024) {
      float v[20]; load20(xr, 2 * idx + xoff, v);
      float lo[4], hv[4]; fir10x2(v, lo, hv);
      st4(S0 + idx, lo);
      if (idx >= 56 && idx < 4152) st4(h0 + A0 + idx, hv);
    }
    __syncthreads();
    for (int idx = 4 * tid; idx < 2084; idx += 1024) {
      float v[20]; load20(S0, 2 * idx, v);
      float lo[4], hv[4]; fir10x2(v, lo, hv);
      st4(S1 + idx, lo);
      if (idx >= 24 && idx < 2072) st4(h1 + A1 + idx, hv);
    }
    __syncthreads();
    for (int idx = 4 * tid; idx < 1036; idx += 1024) {
      float v[20]; load20(S1, 2 * idx, v);
      float lo[4], hv[4]; fir10x2(v, lo, hv);
      st4(S0 + idx, lo);
      if (idx >= 8 && idx < 1032) st4(h2 + A2 + idx, hv);
    }
    __syncthreads();
    for (int idx = 4 * tid; idx < 512; idx += 1024) {
      float v[20]; load20(S0, 2 * idx, v);
      float lo[4], hv[4]; fir10x2(v, lo, hv);
      st4(l3 + b3 + idx, lo);
      st4(h3 + b3 + idx, hv);
    }
  } else {
    {
      const int vlo = -A0, vhi = 65537 - A0;
      const int ee = min(4152, vhi);
      for (int idx = 4 * tid; idx < 4180; idx += 1024) {
        float v[20]; load20z(xr, 2 * idx + xoff, 131072, v);
        float lo[4], hv[4]; fir10x2(v, lo, hv);
        store_pad(S0, idx, lo, vlo, vhi);
        store_hi(h0, A0, idx, hv, 56, ee);
      }
    }
    __syncthreads();
    {
      const int vlo = -A1, vhi = 32769 - A1;
      const int ee = min(2072, vhi);
      for (int idx = 4 * tid; idx < 2084; idx += 1024) {
        float v[20]; load20(S0, 2 * idx, v);
        float lo[4], hv[4]; fir10x2(v, lo, hv);
        store_pad(S1, idx, lo, vlo, vhi);
        store_hi(h1, A1, idx, hv, 24, ee);
      }
    }
    __syncthreads();
    {
      const int vlo = -A2, vhi = 16385 - A2;
      const int ee = min(1032, vhi);
      for (int idx = 4 * tid; idx < 1036; idx += 1024) {
        float v[20]; load20(S1, 2 * idx, v);
        float lo[4], hv[4]; fir10x2(v, lo, hv);
        store_pad(S0, idx, lo, vlo, vhi);
        store_hi(h2, A2, idx, hv, 8, ee);
      }
    }
    __syncthreads();
    {
      const int ne3 = min(512, 8193 - b3);
      for (int idx = 4 * tid; idx < 512; idx += 1024) {
        float v[20]; load20(S0, 2 * idx, v);
        float lo[4], hv[4]; fir10x2(v, lo, hv);
        store_hi(l3, b3, idx, lo, 0, ne3);
        store_hi(h3, b3, idx, hv, 0, ne3);
      }
    }
  }
}

// ---------------- inverse primitives ----------------
__device__ inline void inv_accum(const float* p, const float* h,
                                 const float4* wpk, float* acc) {
#pragma unroll
  for (int i = 0; i < 8; ++i) acc[i] = 0.f;
#pragma unroll
  for (int m = 0; m < 16; ++m) {
    const float4 w = wpk[m];
#pragma unroll
    for (int e = 0; e < 4; ++e) {
      const float pe = p[e + 1 + m], he = h[e + 1 + m];
      acc[2 * e + 0] += pe * w.y + he * w.w;
      acc[2 * e + 1] += pe * w.x + he * w.z;
    }
  }
}

__device__ inline void inv_store_pad(float* S, int o, const float* acc,
                                     int vlo, int vhi) {
  if (o >= vlo && o + 7 < vhi) {
    st4(S + o, acc);
    st4(S + o + 4, acc + 4);
  } else {
#pragma unroll
    for (int i = 0; i < 8; ++i)
      S[o + i] = (o + i >= vlo && o + i < vhi) ? acc[i] : 0.f;
  }
}

// global-source stage (prev3+hi3 -> Sout)
template <bool FAST>
__device__ inline void inv_stage_g(const float* __restrict__ pg,
                                   const float* __restrict__ hig, int Dp,
                                   int P0, float* Sout, int NOUT, int Aout,
                                   int lenOut, const float4* wpk, int tid) {
  const int vlo = -Aout, vhi = lenOut - Aout;
  for (int o = 8 * tid; o < NOUT; o += 2048) {
    const int uh = o >> 1;
    float p[20], h[20];
    if (FAST) {
      load20(pg, P0 + uh, p);
      load20(hig, P0 + uh, h);
    } else {
      load20z(pg, P0 + uh, Dp, p);
      load20z(hig, P0 + uh, Dp, h);
    }
    float acc[8];
    inv_accum(p, h, wpk, acc);
    if (FAST) {
      st4(Sout + o, acc);
      st4(Sout + o + 4, acc + 4);
    } else {
      inv_store_pad(Sout, o, acc, vlo, vhi);
    }
  }
}

// LDS-source stage (Sprev + global hi -> Sout)
template <bool FAST>
__device__ inline void inv_stage_l(const float* Sprev, int reloff,
                                   const float* __restrict__ hig, int Dhi,
                                   int U0, float* Sout, int NOUT, int Aout,
                                   int lenOut, const float4* wpk, int tid) {
  const int vlo = -Aout, vhi = lenOut - Aout;
  for (int o = 8 * tid; o < NOUT; o += 2048) {
    const int uh = o >> 1;
    float p[20], h[20];
    load20(Sprev, uh + reloff, p);
    if (FAST) load20(hig, U0 + uh, h);
    else load20z(hig, U0 + uh, Dhi, h);
    float acc[8];
    inv_accum(p, h, wpk, acc);
    if (FAST) {
      st4(Sout + o, acc);
      st4(Sout + o + 4, acc + 4);
    } else {
      inv_store_pad(Sout, o, acc, vlo, vhi);
    }
  }
}

// final stage (Sprev + global hi0 -> out tile, stores always interior)
template <bool FAST>
__device__ inline void inv_stage_o(const float* Sprev,
                                   const float* __restrict__ hig, int Dhi,
                                   int U0, float* __restrict__ og,
                                   const float4* wpk, int tid) {
  for (int o = 8 * tid; o < 8192; o += 2048) {
    const int uh = o >> 1;
    float p[20], h[20];
    load20(Sprev, uh, p);
    if (FAST) load20(hig, U0 + uh, h);
    else load20z(hig, U0 + uh, Dhi, h);
    float acc[8];
    inv_accum(p, h, wpk, acc);
    st4(og + o, acc);
    st4(og + o + 4, acc + 4);
  }
}

// ---------------- inv levels 3-0 fused, tile 8192, 256 threads ----------------
// X: prev2 1056 then prev0 4112; Y: prev1 2080.
__global__ __launch_bounds__(256) void inv03(
    const float* __restrict__ prev3, const float* __restrict__ hi3,
    const float* __restrict__ hi2, const float* __restrict__ hi1,
    const float* __restrict__ hi0, const float* __restrict__ filt,
    float* __restrict__ out) {
  const int c = blockIdx.y;
  const int bx = blockIdx.x;
  const int t0b = bx * 8192;
  __shared__ float X[4112];
  __shared__ float Y[2080];
  __shared__ float4 wp[64];
  const int tid = threadIdx.x;
  if (tid < 64) {
    const int lvl = tid >> 4, m = tid & 15;
    const float* f = filt + ((size_t)c * 8 + (3 - lvl)) * 64;
    wp[tid] = make_float4(f[2 * m], f[2 * m + 1], f[32 + 2 * m],
                          f[32 + 2 * m + 1]);
  }
  __syncthreads();
  const bool fast = (bx >= 1) && (bx <= 14);
  const float* p3 = prev3 + (size_t)c * 8196;
  const float* h3 = hi3 + (size_t)c * 8196;
  const float* h2 = hi2 + (size_t)c * 16388;
  const float* h1 = hi1 + (size_t)c * 32772;
  const float* h0 = hi0 + (size_t)c * 65540;
  float* og = out + (size_t)c * 131072 + t0b;

  if (fast) {
    inv_stage_g<true>(p3, h3, 8193, t0b / 16 - 16, X, 1056, t0b / 8 - 16,
                      16385, wp, tid);
    __syncthreads();
    inv_stage_l<true>(X, 0, h2, 16385, t0b / 8 - 16, Y, 2080, t0b / 4 - 16,
                      32769, wp + 16, tid);
    __syncthreads();
    inv_stage_l<true>(Y, 4, h1, 32769, t0b / 4 - 12, X, 4112, t0b / 2 - 8,
                      65537, wp + 32, tid);
    __syncthreads();
    inv_stage_o<true>(X, h0, 65537, t0b / 2 - 8, og, wp + 48, tid);
  } else {
    inv_stage_g<false>(p3, h3, 8193, t0b / 16 - 16, X, 1056, t0b / 8 - 16,
                       16385, wp, tid);
    __syncthreads();
    inv_stage_l<false>(X, 0, h2, 16385, t0b / 8 - 16, Y, 2080, t0b / 4 - 16,
                       32769, wp + 16, tid);
    __syncthreads();
    inv_stage_l<false>(Y, 4, h1, 32769, t0b / 4 - 12, X, 4112, t0b / 2 - 8,
                       65537, wp + 32, tid);
    __syncthreads();
    inv_stage_o<false>(X, h0, 65537, t0b / 2 - 8, og, wp + 48, tid);
  }
}

// ---------------- middle: fwd 4-7 + inv 7-4, one block per row ----------------
__device__ inline void fwd_tail_level(const float* __restrict__ in,
                                      float* __restrict__ outp, int L, int D,
                                      float* __restrict__ hirow, int tid) {
  for (int d0 = 4 * tid; d0 < D; d0 += 2048) {
    const int jb = 2 * d0 - 8;
    float v[20];
    const bool interior = (jb >= 0) && (jb + 19 < L) && (d0 + 3 < D);
    if (interior) {
      load20(in, jb, v);
    } else {
#pragma unroll
      for (int q = 0; q < 20; ++q) {
        const int j = jb + q;
        v[q] = (j >= 0 && j < L) ? in[j] : 0.f;
      }
    }
    float lo[4], hv[4];
    fir10x2(v, lo, hv);
    if (interior) {
      st4(outp + d0, lo);
      st4(hirow + d0, hv);
    } else {
#pragma unroll
      for (int i = 0; i < 4; ++i)
        if (d0 + i < D) { outp[d0 + i] = lo[i]; hirow[d0 + i] = hv[i]; }
    }
  }
}

__device__ inline void inv_tail_level(const float* __restrict__ pin,
                                      float* __restrict__ pout, int L,
                                      const float* __restrict__ hirow,
                                      const float* __restrict__ filt, int c,
                                      int level, int tid, float4* wpack) {
  __syncthreads();
  if (tid < 16) {
    const float* f = filt + ((size_t)c * 8 + level) * 64;
    wpack[tid] = make_float4(f[2 * tid], f[2 * tid + 1], f[32 + 2 * tid],
                             f[32 + 2 * tid + 1]);
  }
  __syncthreads();
  const int Tout = 2 * L - 1;
  for (int t0 = 8 * tid; t0 < Tout; t0 += 4096) {
    const int U = t0 / 2 - 8;
    float p[20], h[20];
    if (U >= 0 && U + 19 < L) {
      load20(pin, U, p);
      load20(hirow, U, h);
    } else {
#pragma unroll
      for (int q = 0; q < 20; ++q) {
        const int j = U + q;
        p[q] = (j >= 0 && j < L) ? pin[j] : 0.f;
        h[q] = (j >= 0 && j < L) ? hirow[j] : 0.f;
      }
    }
    float acc[8];
    inv_accum(p, h, wpack, acc);
    if (t0 + 7 < Tout) {
      st4(pout + t0, acc);
      st4(pout + t0 + 4, acc + 4);
    } else {
#pragma unroll
      for (int i = 0; i < 8; ++i)
        if (t0 + i < Tout) pout[t0 + i] = acc[i];
    }
  }
}

__global__ __launch_bounds__(512) void mid_fused(
    const float* __restrict__ lo3, const float* __restrict__ filt,
    float* __restrict__ prev3out) {
  const int b = blockIdx.x;
  __shared__ float A[8200];
  __shared__ float Bb[4104];
  __shared__ float H4[4100];
  __shared__ float H5[2052];
  __shared__ float H6[1028];
  __shared__ float H7[516];
  __shared__ float4 wpack[16];
  const int tid = threadIdx.x;
  const float* row = lo3 + (size_t)b * 8196;
  for (int j4 = tid; j4 < 2048; j4 += 512)
    *reinterpret_cast<float4*>(A + 4 * j4) =
        *reinterpret_cast<const float4*>(row + 4 * j4);
  if (tid == 0) A[8192] = row[8192];
  __syncthreads();
  fwd_tail_level(A, Bb, 8193, 4097, H4, tid);
  __syncthreads();
  fwd_tail_level(Bb, A, 4097, 2049, H5, tid);
  __syncthreads();
  fwd_tail_level(A, Bb, 2049, 1025, H6, tid);
  __syncthreads();
  fwd_tail_level(Bb, A, 1025, 513, H7, tid);
  inv_tail_level(A, Bb, 513, H7, filt, b, 7, tid, wpack);
  inv_tail_level(Bb, A, 1025, H6, filt, b, 6, tid, wpack);
  inv_tail_level(A, Bb, 2049, H5, filt, b, 5, tid, wpack);
  inv_tail_level(Bb, prev3out + (size_t)b * 8196, 4097, H4, filt, b, 4, tid,
                 wpack);
}

extern "C" void kernel_launch(void* const* d_in, const int* in_sizes, int n_in,
                              void* d_out, int out_size, void* d_ws,
                              size_t ws_size, hipStream_t stream) {
  const float* x = (const float*)d_in[0];
  const float* filt = (const float*)d_in[1];
  float* out = (float*)d_out;
  float* ws = (float*)d_ws;

  const int B = 128;
  float* lo3buf = ws;
  float* prev3buf = lo3buf + (size_t)B * 8196;
  float* hi0 = prev3buf + (size_t)B * 8196;
  float* hi1 = hi0 + (size_t)B * 65540;
  float* hi2 = hi1 + (size_t)B * 32772;
  float* hi3 = hi2 + (size_t)B * 16388;

  hipLaunchKernelGGL(fwd03, dim3(17, B), dim3(256), 0, stream, x, hi0, hi1,
                     hi2, hi3, lo3buf);
  hipLaunchKernelGGL(mid_fused, dim3(B), dim3(512), 0, stream, lo3buf, filt,
                     prev3buf);
  hipLaunchKernelGGL(inv03, dim3(16, B), dim3(256), 0, stream, prev3buf, hi3,
                     hi2, hi1, hi0, filt, out);
}

// Round 7
// 135.711 us; speedup vs baseline: 3.0776x; 1.1034x over previous
//
#include <hip/hip_runtime.h>

// 8-level DWT + 8-level per-channel IDWT.
//  fwd03: levels 0-3 halo-fused per 512-wide lo3 tile (unchanged from r6)
//  mid_fused: fwd 4-7 + inv 7-4 per row (unchanged)
//  inverse levels 3..0: FLAT per-level kernels (r4 inv_big) — no LDS pyramid,
//  no barriers, conflict-free; intermediates are L3-resident.

static __constant__ float c_dec_lo[10] = {
    0.003335725285001549f, -0.012580751999015526f, -0.006241490213011705f,
    0.07757149384006515f, -0.03224486958502952f, -0.24229488706619015f,
    0.13842814590110342f, 0.7243085284385744f, 0.6038292697974729f,
    0.160102397974125f};
static __constant__ float c_dec_hi[10] = {
    -0.160102397974125f, 0.6038292697974729f, -0.7243085284385744f,
    0.13842814590110342f, 0.24229488706619015f, -0.03224486958502952f,
    -0.07757149384006515f, -0.006241490213011705f, 0.012580751999015526f,
    0.003335725285001549f};

__device__ inline float4 ldz4(const float* __restrict__ row, int j, int L) {
  if (j >= 0 && j + 3 < L) return *reinterpret_cast<const float4*>(row + j);
  float4 r;
  r.x = (j + 0 >= 0 && j + 0 < L) ? row[j + 0] : 0.f;
  r.y = (j + 1 >= 0 && j + 1 < L) ? row[j + 1] : 0.f;
  r.z = (j + 2 >= 0 && j + 2 < L) ? row[j + 2] : 0.f;
  r.w = (j + 3 >= 0 && j + 3 < L) ? row[j + 3] : 0.f;
  return r;
}

__device__ inline void load20(const float* src, int base, float* v) {
#pragma unroll
  for (int q = 0; q < 5; ++q) {
    const float4 t = *reinterpret_cast<const float4*>(src + base + 4 * q);
    v[4 * q + 0] = t.x; v[4 * q + 1] = t.y;
    v[4 * q + 2] = t.z; v[4 * q + 3] = t.w;
  }
}

__device__ inline void load20z(const float* __restrict__ src, int base, int L,
                               float* v) {
#pragma unroll
  for (int q = 0; q < 5; ++q) {
    const float4 t = ldz4(src, base + 4 * q, L);
    v[4 * q + 0] = t.x; v[4 * q + 1] = t.y;
    v[4 * q + 2] = t.z; v[4 * q + 3] = t.w;
  }
}

__device__ inline void fir10x2(const float* v, float* lo, float* hv) {
#pragma unroll
  for (int i = 0; i < 4; ++i) {
    float a = 0.f, h = 0.f;
#pragma unroll
    for (int k = 0; k < 10; ++k) {
      const float xx = v[2 * i + 3 + k];
      a += xx * c_dec_lo[k];
      h += xx * c_dec_hi[k];
    }
    lo[i] = a; hv[i] = h;
  }
}

__device__ inline void store_pad(float* S, int idx, const float* lo, int vlo,
                                 int vhi) {
  if (idx >= vlo && idx + 3 < vhi) {
    *reinterpret_cast<float4*>(S + idx) =
        make_float4(lo[0], lo[1], lo[2], lo[3]);
  } else {
#pragma unroll
    for (int i = 0; i < 4; ++i)
      S[idx + i] = (idx + i >= vlo && idx + i < vhi) ? lo[i] : 0.f;
  }
}

__device__ inline void store_hi(float* hg, int A, int idx, const float* hv,
                                int es, int ee) {
  if (idx >= es && idx + 3 < ee) {
    *reinterpret_cast<float4*>(hg + A + idx) =
        make_float4(hv[0], hv[1], hv[2], hv[3]);
  } else {
#pragma unroll
    for (int i = 0; i < 4; ++i)
      if (idx + i >= es && idx + i < ee) hg[A + idx + i] = hv[i];
  }
}

__device__ inline void st4(float* dst, const float* a) {
  *reinterpret_cast<float4*>(dst) = make_float4(a[0], a[1], a[2], a[3]);
}

// ---------------- fwd levels 0-3 fused, tile 512, 256 threads ----------------
__global__ __launch_bounds__(256) void fwd03(
    const float* __restrict__ x, float* __restrict__ hi0,
    float* __restrict__ hi1, float* __restrict__ hi2,
    float* __restrict__ hi3, float* __restrict__ lo3) {
  const int b = blockIdx.y;
  const int bx = blockIdx.x;
  const int b3 = bx * 512;
  __shared__ float S0[4180];
  __shared__ float S1[2084];
  const int tid = threadIdx.x;
  const bool fast = (bx >= 1) && (bx <= 14);
  const float* xr = x + (size_t)b * 131072;
  float* h0 = hi0 + (size_t)b * 65540;
  float* h1 = hi1 + (size_t)b * 32772;
  float* h2 = hi2 + (size_t)b * 16388;
  float* h3 = hi3 + (size_t)b * 8196;
  float* l3 = lo3 + (size_t)b * 8196;
  const int A0 = 8 * b3 - 56, A1 = 4 * b3 - 24, A2 = 2 * b3 - 8;
  const int xoff = 2 * A0 - 8;

  if (fast) {
    for (int idx = 4 * tid; idx < 4180; idx += 1024) {
      float v[20]; load20(xr, 2 * idx + xoff, v);
      float lo[4], hv[4]; fir10x2(v, lo, hv);
      st4(S0 + idx, lo);
      if (idx >= 56 && idx < 4152) st4(h0 + A0 + idx, hv);
    }
    __syncthreads();
    for (int idx = 4 * tid; idx < 2084; idx += 1024) {
      float v[20]; load20(S0, 2 * idx, v);
      float lo[4], hv[4]; fir10x2(v, lo, hv);
      st4(S1 + idx, lo);
      if (idx >= 24 && idx < 2072) st4(h1 + A1 + idx, hv);
    }
    __syncthreads();
    for (int idx = 4 * tid; idx < 1036; idx += 1024) {
      float v[20]; load20(S1, 2 * idx, v);
      float lo[4], hv[4]; fir10x2(v, lo, hv);
      st4(S0 + idx, lo);
      if (idx >= 8 && idx < 1032) st4(h2 + A2 + idx, hv);
    }
    __syncthreads();
    for (int idx = 4 * tid; idx < 512; idx += 1024) {
      float v[20]; load20(S0, 2 * idx, v);
      float lo[4], hv[4]; fir10x2(v, lo, hv);
      st4(l3 + b3 + idx, lo);
      st4(h3 + b3 + idx, hv);
    }
  } else {
    {
      const int vlo = -A0, vhi = 65537 - A0;
      const int ee = min(4152, vhi);
      for (int idx = 4 * tid; idx < 4180; idx += 1024) {
        float v[20]; load20z(xr, 2 * idx + xoff, 131072, v);
        float lo[4], hv[4]; fir10x2(v, lo, hv);
        store_pad(S0, idx, lo, vlo, vhi);
        store_hi(h0, A0, idx, hv, 56, ee);
      }
    }
    __syncthreads();
    {
      const int vlo = -A1, vhi = 32769 - A1;
      const int ee = min(2072, vhi);
      for (int idx = 4 * tid; idx < 2084; idx += 1024) {
        float v[20]; load20(S0, 2 * idx, v);
        float lo[4], hv[4]; fir10x2(v, lo, hv);
        store_pad(S1, idx, lo, vlo, vhi);
        store_hi(h1, A1, idx, hv, 24, ee);
      }
    }
    __syncthreads();
    {
      const int vlo = -A2, vhi = 16385 - A2;
      const int ee = min(1032, vhi);
      for (int idx = 4 * tid; idx < 1036; idx += 1024) {
        float v[20]; load20(S1, 2 * idx, v);
        float lo[4], hv[4]; fir10x2(v, lo, hv);
        store_pad(S0, idx, lo, vlo, vhi);
        store_hi(h2, A2, idx, hv, 8, ee);
      }
    }
    __syncthreads();
    {
      const int ne3 = min(512, 8193 - b3);
      for (int idx = 4 * tid; idx < 512; idx += 1024) {
        float v[20]; load20(S0, 2 * idx, v);
        float lo[4], hv[4]; fir10x2(v, lo, hv);
        store_hi(l3, b3, idx, lo, 0, ne3);
        store_hi(h3, b3, idx, hv, 0, ne3);
      }
    }
  }
}

// ---------------- 8-output inverse accumulator (used by mid tail) -----------
__device__ inline void inv_accum(const float* p, const float* h,
                                 const float4* wpk, float* acc) {
#pragma unroll
  for (int i = 0; i < 8; ++i) acc[i] = 0.f;
#pragma unroll
  for (int m = 0; m < 16; ++m) {
    const float4 w = wpk[m];
#pragma unroll
    for (int e = 0; e < 4; ++e) {
      const float pe = p[e + 1 + m], he = h[e + 1 + m];
      acc[2 * e + 0] += pe * w.y + he * w.w;
      acc[2 * e + 1] += pe * w.x + he * w.z;
    }
  }
}

// ---------------- flat big inverse level: 16 outputs/thread -----------------
__global__ __launch_bounds__(256) void inv_big(
    const float* __restrict__ prev, const float* __restrict__ hicoef,
    const float* __restrict__ filt, int level, int L, int sIn, int Tout,
    int sOut, float* __restrict__ out) {
  const int c = blockIdx.y;
  __shared__ float4 wpack[16];  // {lo[2m], lo[2m+1], hi[2m], hi[2m+1]}
  const int tid = threadIdx.x;
  if (tid < 16) {
    const float* f = filt + ((size_t)c * 8 + level) * 64;
    wpack[tid] = make_float4(f[2 * tid], f[2 * tid + 1],
                             f[32 + 2 * tid], f[32 + 2 * tid + 1]);
  }
  __syncthreads();
  const int g = blockIdx.x * 256 + tid;
  const int t0 = 16 * g;
  if (t0 >= Tout) return;
  const int U = 8 * g - 8;
  const float* prow = prev + (size_t)c * sIn;
  const float* hrow = hicoef + (size_t)c * sIn;
  float p[24], h[24];
  const bool interior = (U >= 0) && (U + 23 < L) && (t0 + 15 < Tout);
  if (interior) {
#pragma unroll
    for (int q = 0; q < 6; ++q) {
      float4 a = *reinterpret_cast<const float4*>(prow + U + 4 * q);
      p[4 * q + 0] = a.x; p[4 * q + 1] = a.y; p[4 * q + 2] = a.z; p[4 * q + 3] = a.w;
      float4 bb = *reinterpret_cast<const float4*>(hrow + U + 4 * q);
      h[4 * q + 0] = bb.x; h[4 * q + 1] = bb.y; h[4 * q + 2] = bb.z; h[4 * q + 3] = bb.w;
    }
  } else {
#pragma unroll
    for (int q = 0; q < 24; ++q) {
      const int j = U + q;
      p[q] = (j >= 0 && j < L) ? prow[j] : 0.f;
      h[q] = (j >= 0 && j < L) ? hrow[j] : 0.f;
    }
  }
  float acc[16];
#pragma unroll
  for (int i = 0; i < 16; ++i) acc[i] = 0.f;
#pragma unroll
  for (int m = 0; m < 16; ++m) {
    const float4 w = wpack[m];
#pragma unroll
    for (int e = 0; e < 8; ++e) {
      const float pv = p[e + 1 + m], hv = h[e + 1 + m];
      acc[2 * e + 0] += pv * w.y + hv * w.w;
      acc[2 * e + 1] += pv * w.x + hv * w.z;
    }
  }
  float* orow = out + (size_t)c * sOut;
  if (interior) {
#pragma unroll
    for (int q = 0; q < 4; ++q)
      *reinterpret_cast<float4*>(orow + t0 + 4 * q) =
          make_float4(acc[4 * q], acc[4 * q + 1], acc[4 * q + 2], acc[4 * q + 3]);
  } else {
#pragma unroll
    for (int i = 0; i < 16; ++i)
      if (t0 + i < Tout) orow[t0 + i] = acc[i];
  }
}

// ---------------- middle: fwd 4-7 + inv 7-4, one block per row --------------
__device__ inline void fwd_tail_level(const float* __restrict__ in,
                                      float* __restrict__ outp, int L, int D,
                                      float* __restrict__ hirow, int tid) {
  for (int d0 = 4 * tid; d0 < D; d0 += 2048) {
    const int jb = 2 * d0 - 8;
    float v[20];
    const bool interior = (jb >= 0) && (jb + 19 < L) && (d0 + 3 < D);
    if (interior) {
      load20(in, jb, v);
    } else {
#pragma unroll
      for (int q = 0; q < 20; ++q) {
        const int j = jb + q;
        v[q] = (j >= 0 && j < L) ? in[j] : 0.f;
      }
    }
    float lo[4], hv[4];
    fir10x2(v, lo, hv);
    if (interior) {
      st4(outp + d0, lo);
      st4(hirow + d0, hv);
    } else {
#pragma unroll
      for (int i = 0; i < 4; ++i)
        if (d0 + i < D) { outp[d0 + i] = lo[i]; hirow[d0 + i] = hv[i]; }
    }
  }
}

__device__ inline void inv_tail_level(const float* __restrict__ pin,
                                      float* __restrict__ pout, int L,
                                      const float* __restrict__ hirow,
                                      const float* __restrict__ filt, int c,
                                      int level, int tid, float4* wpack) {
  __syncthreads();
  if (tid < 16) {
    const float* f = filt + ((size_t)c * 8 + level) * 64;
    wpack[tid] = make_float4(f[2 * tid], f[2 * tid + 1], f[32 + 2 * tid],
                             f[32 + 2 * tid + 1]);
  }
  __syncthreads();
  const int Tout = 2 * L - 1;
  for (int t0 = 8 * tid; t0 < Tout; t0 += 4096) {
    const int U = t0 / 2 - 8;
    float p[20], h[20];
    if (U >= 0 && U + 19 < L) {
      load20(pin, U, p);
      load20(hirow, U, h);
    } else {
#pragma unroll
      for (int q = 0; q < 20; ++q) {
        const int j = U + q;
        p[q] = (j >= 0 && j < L) ? pin[j] : 0.f;
        h[q] = (j >= 0 && j < L) ? hirow[j] : 0.f;
      }
    }
    float acc[8];
    inv_accum(p, h, wpack, acc);
    if (t0 + 7 < Tout) {
      st4(pout + t0, acc);
      st4(pout + t0 + 4, acc + 4);
    } else {
#pragma unroll
      for (int i = 0; i < 8; ++i)
        if (t0 + i < Tout) pout[t0 + i] = acc[i];
    }
  }
}

__global__ __launch_bounds__(512) void mid_fused(
    const float* __restrict__ lo3, const float* __restrict__ filt,
    float* __restrict__ prev3out) {
  const int b = blockIdx.x;
  __shared__ float A[8200];
  __shared__ float Bb[4104];
  __shared__ float H4[4100];
  __shared__ float H5[2052];
  __shared__ float H6[1028];
  __shared__ float H7[516];
  __shared__ float4 wpack[16];
  const int tid = threadIdx.x;
  const float* row = lo3 + (size_t)b * 8196;
  for (int j4 = tid; j4 < 2048; j4 += 512)
    *reinterpret_cast<float4*>(A + 4 * j4) =
        *reinterpret_cast<const float4*>(row + 4 * j4);
  if (tid == 0) A[8192] = row[8192];
  __syncthreads();
  fwd_tail_level(A, Bb, 8193, 4097, H4, tid);
  __syncthreads();
  fwd_tail_level(Bb, A, 4097, 2049, H5, tid);
  __syncthreads();
  fwd_tail_level(A, Bb, 2049, 1025, H6, tid);
  __syncthreads();
  fwd_tail_level(Bb, A, 1025, 513, H7, tid);
  inv_tail_level(A, Bb, 513, H7, filt, b, 7, tid, wpack);
  inv_tail_level(Bb, A, 1025, H6, filt, b, 6, tid, wpack);
  inv_tail_level(A, Bb, 2049, H5, filt, b, 5, tid, wpack);
  inv_tail_level(Bb, prev3out + (size_t)b * 8196, 4097, H4, filt, b, 4, tid,
                 wpack);
}

extern "C" void kernel_launch(void* const* d_in, const int* in_sizes, int n_in,
                              void* d_out, int out_size, void* d_ws,
                              size_t ws_size, hipStream_t stream) {
  const float* x = (const float*)d_in[0];
  const float* filt = (const float*)d_in[1];
  float* out = (float*)d_out;
  float* ws = (float*)d_ws;

  const int B = 128;
  float* lo3buf = ws;
  float* prev3buf = lo3buf + (size_t)B * 8196;
  float* hi0 = prev3buf + (size_t)B * 8196;
  float* hi1 = hi0 + (size_t)B * 65540;
  float* hi2 = hi1 + (size_t)B * 32772;
  float* hi3 = hi2 + (size_t)B * 16388;
  float* prev2buf = hi3 + (size_t)B * 8196;
  float* prev1buf = prev2buf + (size_t)B * 16388;
  float* prev0buf = prev1buf + (size_t)B * 32772;

  hipLaunchKernelGGL(fwd03, dim3(17, B), dim3(256), 0, stream, x, hi0, hi1,
                     hi2, hi3, lo3buf);
  hipLaunchKernelGGL(mid_fused, dim3(B), dim3(512), 0, stream, lo3buf, filt,
                     prev3buf);

  auto launch_inv = [&](const float* prev, const float* hv, int level, int L,
                        int sIn, int Tout, int sOut, float* dst) {
    const int tpr = (Tout + 15) / 16;
    dim3 grid((tpr + 255) / 256, B);
    hipLaunchKernelGGL(inv_big, grid, dim3(256), 0, stream, prev, hv, filt,
                       level, L, sIn, Tout, sOut, dst);
  };
  // inverse levels 3..0 (flat)
  launch_inv(prev3buf, hi3, 3, 8193, 8196, 16385, 16388, prev2buf);
  launch_inv(prev2buf, hi2, 2, 16385, 16388, 32769, 32772, prev1buf);
  launch_inv(prev1buf, hi1, 1, 32769, 32772, 65537, 65540, prev0buf);
  launch_inv(prev0buf, hi0, 0, 65537, 65540, 131072, 131072, out);
}

// Round 8
// 133.355 us; speedup vs baseline: 3.1320x; 1.0177x over previous
//
#include <hip/hip_runtime.h>

// 8-level DWT + 8-level per-channel IDWT.
//  fwd03: levels 0-3 halo-fused per 512-wide lo3 tile. Levels 1-3 use
//         EVEN/ODD-SPLIT LDS (E[j]=lo[2j], O[j]=lo[2j+1]) so decimating
//         window reads are 16B/lane stride -> bank-conflict-free.
//  mid_fused: fwd 4-7 + inv 7-4 per row (unchanged).
//  inverse levels 3..0: flat per-level kernels (unchanged).

static __constant__ float c_dec_lo[10] = {
    0.003335725285001549f, -0.012580751999015526f, -0.006241490213011705f,
    0.07757149384006515f, -0.03224486958502952f, -0.24229488706619015f,
    0.13842814590110342f, 0.7243085284385744f, 0.6038292697974729f,
    0.160102397974125f};
static __constant__ float c_dec_hi[10] = {
    -0.160102397974125f, 0.6038292697974729f, -0.7243085284385744f,
    0.13842814590110342f, 0.24229488706619015f, -0.03224486958502952f,
    -0.07757149384006515f, -0.006241490213011705f, 0.012580751999015526f,
    0.003335725285001549f};

__device__ inline float4 ldz4(const float* __restrict__ row, int j, int L) {
  if (j >= 0 && j + 3 < L) return *reinterpret_cast<const float4*>(row + j);
  float4 r;
  r.x = (j + 0 >= 0 && j + 0 < L) ? row[j + 0] : 0.f;
  r.y = (j + 1 >= 0 && j + 1 < L) ? row[j + 1] : 0.f;
  r.z = (j + 2 >= 0 && j + 2 < L) ? row[j + 2] : 0.f;
  r.w = (j + 3 >= 0 && j + 3 < L) ? row[j + 3] : 0.f;
  return r;
}

__device__ inline void load20(const float* src, int base, float* v) {
#pragma unroll
  for (int q = 0; q < 5; ++q) {
    const float4 t = *reinterpret_cast<const float4*>(src + base + 4 * q);
    v[4 * q + 0] = t.x; v[4 * q + 1] = t.y;
    v[4 * q + 2] = t.z; v[4 * q + 3] = t.w;
  }
}

__device__ inline void load20z(const float* __restrict__ src, int base, int L,
                               float* v) {
#pragma unroll
  for (int q = 0; q < 5; ++q) {
    const float4 t = ldz4(src, base + 4 * q, L);
    v[4 * q + 0] = t.x; v[4 * q + 1] = t.y;
    v[4 * q + 2] = t.z; v[4 * q + 3] = t.w;
  }
}

__device__ inline void load12(const float* src, float* v) {
#pragma unroll
  for (int q = 0; q < 3; ++q) {
    const float4 t = *reinterpret_cast<const float4*>(src + 4 * q);
    v[4 * q + 0] = t.x; v[4 * q + 1] = t.y;
    v[4 * q + 2] = t.z; v[4 * q + 3] = t.w;
  }
}

__device__ inline void fir10x2(const float* v, float* lo, float* hv) {
#pragma unroll
  for (int i = 0; i < 4; ++i) {
    float a = 0.f, h = 0.f;
#pragma unroll
    for (int k = 0; k < 10; ++k) {
      const float xx = v[2 * i + 3 + k];
      a += xx * c_dec_lo[k];
      h += xx * c_dec_hi[k];
    }
    lo[i] = a; hv[i] = h;
  }
}

// Split-form FIR: lo[i] = sum_m o[i+1+m]*w[2m] + e[i+2+m]*w[2m+1]
__device__ inline void fir10x2_split(const float* e, const float* o,
                                     float* lo, float* hv) {
#pragma unroll
  for (int i = 0; i < 4; ++i) {
    float a = 0.f, h = 0.f;
#pragma unroll
    for (int m = 0; m < 5; ++m) {
      const float ov = o[i + 1 + m], ev = e[i + 2 + m];
      a += ov * c_dec_lo[2 * m] + ev * c_dec_lo[2 * m + 1];
      h += ov * c_dec_hi[2 * m] + ev * c_dec_hi[2 * m + 1];
    }
    lo[i] = a; hv[i] = h;
  }
}

__device__ inline void store_hi(float* hg, int A, int idx, const float* hv,
                                int es, int ee) {
  if (idx >= es && idx + 3 < ee) {
    *reinterpret_cast<float4*>(hg + A + idx) =
        make_float4(hv[0], hv[1], hv[2], hv[3]);
  } else {
#pragma unroll
    for (int i = 0; i < 4; ++i)
      if (idx + i >= es && idx + i < ee) hg[A + idx + i] = hv[i];
  }
}

__device__ inline void st4(float* dst, const float* a) {
  *reinterpret_cast<float4*>(dst) = make_float4(a[0], a[1], a[2], a[3]);
}

// Write 4 consecutive S-positions idx..idx+3 into split E/O with zero-pad.
__device__ inline void store_pad_split(float* E, float* O, int idx,
                                       const float* lo, int vlo, int vhi) {
#pragma unroll
  for (int i = 0; i < 4; ++i) {
    const int s = idx + i;
    const float val = (s >= vlo && s < vhi) ? lo[i] : 0.f;
    if (s & 1) O[s >> 1] = val;
    else E[s >> 1] = val;
  }
}

// ---------------- fwd levels 0-3 fused (split-LDS), tile 512 ----------------
template <bool FAST>
__device__ inline void fwd_level0(const float* __restrict__ xr, float* E0,
                                  float* O0, float* __restrict__ h0, int A0,
                                  int xoff, int vlo, int vhi, int tid) {
  const int ee = FAST ? 4152 : min(4152, vhi);
  for (int idx = 4 * tid; idx < 4180; idx += 1024) {
    float v[20];
    if (FAST) load20(xr, 2 * idx + xoff, v);
    else load20z(xr, 2 * idx + xoff, 131072, v);
    float lo[4], hv[4];
    fir10x2(v, lo, hv);
    if (FAST) {
      const int j = idx >> 1;
      *reinterpret_cast<float2*>(E0 + j) = make_float2(lo[0], lo[2]);
      *reinterpret_cast<float2*>(O0 + j) = make_float2(lo[1], lo[3]);
      if (idx >= 56 && idx < 4152) st4(h0 + A0 + idx, hv);
    } else {
      store_pad_split(E0, O0, idx, lo, vlo, vhi);
      store_hi(h0, A0, idx, hv, 56, ee);
    }
  }
}

template <bool FAST>
__device__ inline void fwd_levelN(const float* Ein, const float* Oin,
                                  float* Eout, float* Oout,
                                  float* __restrict__ hg, int A, int NOUT,
                                  int esHi, int eeFast, int vlo, int vhi,
                                  int tid) {
  const int ee = FAST ? eeFast : min(eeFast, vhi);
  for (int idx = 4 * tid; idx < NOUT; idx += 1024) {
    float e[12], o[12];
    load12(Ein + idx, e);
    load12(Oin + idx, o);
    float lo[4], hv[4];
    fir10x2_split(e, o, lo, hv);
    if (FAST) {
      const int j = idx >> 1;
      *reinterpret_cast<float2*>(Eout + j) = make_float2(lo[0], lo[2]);
      *reinterpret_cast<float2*>(Oout + j) = make_float2(lo[1], lo[3]);
      if (idx >= esHi && idx < ee) st4(hg + A + idx, hv);
    } else {
      store_pad_split(Eout, Oout, idx, lo, vlo, vhi);
      store_hi(hg, A, idx, hv, esHi, ee);
    }
  }
}

template <bool FAST>
__device__ inline void fwd_level3(const float* Ein, const float* Oin,
                                  float* __restrict__ l3,
                                  float* __restrict__ h3, int b3, int ne3,
                                  int tid) {
  for (int idx = 4 * tid; idx < 512; idx += 1024) {
    float e[12], o[12];
    load12(Ein + idx, e);
    load12(Oin + idx, o);
    float lo[4], hv[4];
    fir10x2_split(e, o, lo, hv);
    if (FAST) {
      st4(l3 + b3 + idx, lo);
      st4(h3 + b3 + idx, hv);
    } else {
      store_hi(l3, b3, idx, lo, 0, ne3);
      store_hi(h3, b3, idx, hv, 0, ne3);
    }
  }
}

__global__ __launch_bounds__(256) void fwd03(
    const float* __restrict__ x, float* __restrict__ hi0,
    float* __restrict__ hi1, float* __restrict__ hi2,
    float* __restrict__ hi3, float* __restrict__ lo3) {
  const int b = blockIdx.y;
  const int bx = blockIdx.x;
  const int b3 = bx * 512;
  __shared__ float E0[2092], O0[2092];
  __shared__ float E1[1044], O1[1044];
  __shared__ float E2[520], O2[520];
  const int tid = threadIdx.x;
  const bool fast = (bx >= 1) && (bx <= 14);
  const float* xr = x + (size_t)b * 131072;
  float* h0 = hi0 + (size_t)b * 65540;
  float* h1 = hi1 + (size_t)b * 32772;
  float* h2 = hi2 + (size_t)b * 16388;
  float* h3 = hi3 + (size_t)b * 8196;
  float* l3 = lo3 + (size_t)b * 8196;
  const int A0 = 8 * b3 - 56, A1 = 4 * b3 - 24, A2 = 2 * b3 - 8;
  const int xoff = 2 * A0 - 8;

  if (fast) {
    fwd_level0<true>(xr, E0, O0, h0, A0, xoff, 0, 0, tid);
    __syncthreads();
    fwd_levelN<true>(E0, O0, E1, O1, h1, A1, 2084, 24, 2072, 0, 0, tid);
    __syncthreads();
    fwd_levelN<true>(E1, O1, E2, O2, h2, A2, 1036, 8, 1032, 0, 0, tid);
    __syncthreads();
    fwd_level3<true>(E2, O2, l3, h3, b3, 512, tid);
  } else {
    fwd_level0<false>(xr, E0, O0, h0, A0, xoff, -A0, 65537 - A0, tid);
    __syncthreads();
    fwd_levelN<false>(E0, O0, E1, O1, h1, A1, 2084, 24, 2072, -A1,
                      32769 - A1, tid);
    __syncthreads();
    fwd_levelN<false>(E1, O1, E2, O2, h2, A2, 1036, 8, 1032, -A2, 16385 - A2,
                      tid);
    __syncthreads();
    fwd_level3<false>(E2, O2, l3, h3, b3, min(512, 8193 - b3), tid);
  }
}

// ---------------- 8-output inverse accumulator (used by mid tail) -----------
__device__ inline void inv_accum(const float* p, const float* h,
                                 const float4* wpk, float* acc) {
#pragma unroll
  for (int i = 0; i < 8; ++i) acc[i] = 0.f;
#pragma unroll
  for (int m = 0; m < 16; ++m) {
    const float4 w = wpk[m];
#pragma unroll
    for (int e = 0; e < 4; ++e) {
      const float pe = p[e + 1 + m], he = h[e + 1 + m];
      acc[2 * e + 0] += pe * w.y + he * w.w;
      acc[2 * e + 1] += pe * w.x + he * w.z;
    }
  }
}

// ---------------- flat big inverse level: 16 outputs/thread -----------------
__global__ __launch_bounds__(256) void inv_big(
    const float* __restrict__ prev, const float* __restrict__ hicoef,
    const float* __restrict__ filt, int level, int L, int sIn, int Tout,
    int sOut, float* __restrict__ out) {
  const int c = blockIdx.y;
  __shared__ float4 wpack[16];
  const int tid = threadIdx.x;
  if (tid < 16) {
    const float* f = filt + ((size_t)c * 8 + level) * 64;
    wpack[tid] = make_float4(f[2 * tid], f[2 * tid + 1],
                             f[32 + 2 * tid], f[32 + 2 * tid + 1]);
  }
  __syncthreads();
  const int g = blockIdx.x * 256 + tid;
  const int t0 = 16 * g;
  if (t0 >= Tout) return;
  const int U = 8 * g - 8;
  const float* prow = prev + (size_t)c * sIn;
  const float* hrow = hicoef + (size_t)c * sIn;
  float p[24], h[24];
  const bool interior = (U >= 0) && (U + 23 < L) && (t0 + 15 < Tout);
  if (interior) {
#pragma unroll
    for (int q = 0; q < 6; ++q) {
      float4 a = *reinterpret_cast<const float4*>(prow + U + 4 * q);
      p[4 * q + 0] = a.x; p[4 * q + 1] = a.y; p[4 * q + 2] = a.z; p[4 * q + 3] = a.w;
      float4 bb = *reinterpret_cast<const float4*>(hrow + U + 4 * q);
      h[4 * q + 0] = bb.x; h[4 * q + 1] = bb.y; h[4 * q + 2] = bb.z; h[4 * q + 3] = bb.w;
    }
  } else {
#pragma unroll
    for (int q = 0; q < 24; ++q) {
      const int j = U + q;
      p[q] = (j >= 0 && j < L) ? prow[j] : 0.f;
      h[q] = (j >= 0 && j < L) ? hrow[j] : 0.f;
    }
  }
  float acc[16];
#pragma unroll
  for (int i = 0; i < 16; ++i) acc[i] = 0.f;
#pragma unroll
  for (int m = 0; m < 16; ++m) {
    const float4 w = wpack[m];
#pragma unroll
    for (int e = 0; e < 8; ++e) {
      const float pv = p[e + 1 + m], hv = h[e + 1 + m];
      acc[2 * e + 0] += pv * w.y + hv * w.w;
      acc[2 * e + 1] += pv * w.x + hv * w.z;
    }
  }
  float* orow = out + (size_t)c * sOut;
  if (interior) {
#pragma unroll
    for (int q = 0; q < 4; ++q)
      *reinterpret_cast<float4*>(orow + t0 + 4 * q) =
          make_float4(acc[4 * q], acc[4 * q + 1], acc[4 * q + 2], acc[4 * q + 3]);
  } else {
#pragma unroll
    for (int i = 0; i < 16; ++i)
      if (t0 + i < Tout) orow[t0 + i] = acc[i];
  }
}

// ---------------- middle: fwd 4-7 + inv 7-4, one block per row --------------
__device__ inline void fwd_tail_level(const float* __restrict__ in,
                                      float* __restrict__ outp, int L, int D,
                                      float* __restrict__ hirow, int tid) {
  for (int d0 = 4 * tid; d0 < D; d0 += 2048) {
    const int jb = 2 * d0 - 8;
    float v[20];
    const bool interior = (jb >= 0) && (jb + 19 < L) && (d0 + 3 < D);
    if (interior) {
      load20(in, jb, v);
    } else {
#pragma unroll
      for (int q = 0; q < 20; ++q) {
        const int j = jb + q;
        v[q] = (j >= 0 && j < L) ? in[j] : 0.f;
      }
    }
    float lo[4], hv[4];
    fir10x2(v, lo, hv);
    if (interior) {
      st4(outp + d0, lo);
      st4(hirow + d0, hv);
    } else {
#pragma unroll
      for (int i = 0; i < 4; ++i)
        if (d0 + i < D) { outp[d0 + i] = lo[i]; hirow[d0 + i] = hv[i]; }
    }
  }
}

__device__ inline void inv_tail_level(const float* __restrict__ pin,
                                      float* __restrict__ pout, int L,
                                      const float* __restrict__ hirow,
                                      const float* __restrict__ filt, int c,
                                      int level, int tid, float4* wpack) {
  __syncthreads();
  if (tid < 16) {
    const float* f = filt + ((size_t)c * 8 + level) * 64;
    wpack[tid] = make_float4(f[2 * tid], f[2 * tid + 1], f[32 + 2 * tid],
                             f[32 + 2 * tid + 1]);
  }
  __syncthreads();
  const int Tout = 2 * L - 1;
  for (int t0 = 8 * tid; t0 < Tout; t0 += 4096) {
    const int U = t0 / 2 - 8;
    float p[20], h[20];
    if (U >= 0 && U + 19 < L) {
      load20(pin, U, p);
      load20(hirow, U, h);
    } else {
#pragma unroll
      for (int q = 0; q < 20; ++q) {
        const int j = U + q;
        p[q] = (j >= 0 && j < L) ? pin[j] : 0.f;
        h[q] = (j >= 0 && j < L) ? hirow[j] : 0.f;
      }
    }
    float acc[8];
    inv_accum(p, h, wpack, acc);
    if (t0 + 7 < Tout) {
      st4(pout + t0, acc);
      st4(pout + t0 + 4, acc + 4);
    } else {
#pragma unroll
      for (int i = 0; i < 8; ++i)
        if (t0 + i < Tout) pout[t0 + i] = acc[i];
    }
  }
}

__global__ __launch_bounds__(512) void mid_fused(
    const float* __restrict__ lo3, const float* __restrict__ filt,
    float* __restrict__ prev3out) {
  const int b = blockIdx.x;
  __shared__ float A[8200];
  __shared__ float Bb[4104];
  __shared__ float H4[4100];
  __shared__ float H5[2052];
  __shared__ float H6[1028];
  __shared__ float H7[516];
  __shared__ float4 wpack[16];
  const int tid = threadIdx.x;
  const float* row = lo3 + (size_t)b * 8196;
  for (int j4 = tid; j4 < 2048; j4 += 512)
    *reinterpret_cast<float4*>(A + 4 * j4) =
        *reinterpret_cast<const float4*>(row + 4 * j4);
  if (tid == 0) A[8192] = row[8192];
  __syncthreads();
  fwd_tail_level(A, Bb, 8193, 4097, H4, tid);
  __syncthreads();
  fwd_tail_level(Bb, A, 4097, 2049, H5, tid);
  __syncthreads();
  fwd_tail_level(A, Bb, 2049, 1025, H6, tid);
  __syncthreads();
  fwd_tail_level(Bb, A, 1025, 513, H7, tid);
  inv_tail_level(A, Bb, 513, H7, filt, b, 7, tid, wpack);
  inv_tail_level(Bb, A, 1025, H6, filt, b, 6, tid, wpack);
  inv_tail_level(A, Bb, 2049, H5, filt, b, 5, tid, wpack);
  inv_tail_level(Bb, prev3out + (size_t)b * 8196, 4097, H4, filt, b, 4, tid,
                 wpack);
}

extern "C" void kernel_launch(void* const* d_in, const int* in_sizes, int n_in,
                              void* d_out, int out_size, void* d_ws,
                              size_t ws_size, hipStream_t stream) {
  const float* x = (const float*)d_in[0];
  const float* filt = (const float*)d_in[1];
  float* out = (float*)d_out;
  float* ws = (float*)d_ws;

  const int B = 128;
  float* lo3buf = ws;
  float* prev3buf = lo3buf + (size_t)B * 8196;
  float* hi0 = prev3buf + (size_t)B * 8196;
  float* hi1 = hi0 + (size_t)B * 65540;
  float* hi2 = hi1 + (size_t)B * 32772;
  float* hi3 = hi2 + (size_t)B * 16388;
  float* prev2buf = hi3 + (size_t)B * 8196;
  float* prev1buf = prev2buf + (size_t)B * 16388;
  float* prev0buf = prev1buf + (size_t)B * 32772;

  hipLaunchKernelGGL(fwd03, dim3(17, B), dim3(256), 0, stream, x, hi0, hi1,
                     hi2, hi3, lo3buf);
  hipLaunchKernelGGL(mid_fused, dim3(B), dim3(512), 0, stream, lo3buf, filt,
                     prev3buf);

  auto launch_inv = [&](const float* prev, const float* hv, int level, int L,
                        int sIn, int Tout, int sOut, float* dst) {
    const int tpr = (Tout + 15) / 16;
    dim3 grid((tpr + 255) / 256, B);
    hipLaunchKernelGGL(inv_big, grid, dim3(256), 0, stream, prev, hv, filt,
                       level, L, sIn, Tout, sOut, dst);
  };
  // inverse levels 3..0 (flat)
  launch_inv(prev3buf, hi3, 3, 8193, 8196, 16385, 16388, prev2buf);
  launch_inv(prev2buf, hi2, 2, 16385, 16388, 32769, 32772, prev1buf);
  launch_inv(prev1buf, hi1, 1, 32769, 32772, 65537, 65540, prev0buf);
  launch_inv(prev0buf, hi0, 0, 65537, 65540, 131072, 131072, out);
}